// Round 1
// baseline (1333.996 us; speedup 1.0000x reference)
//
#include <hip/hip_runtime.h>
#include <math.h>

typedef unsigned int u32;
typedef unsigned long long u64;
typedef unsigned short u16;
typedef short bf16x8 __attribute__((ext_vector_type(8)));
typedef float f32x4 __attribute__((ext_vector_type(4)));

#define RR 8
#define NN 128
#define DD 512
#define HH 256
#define KTOP 64
#define NCAND 256    // candidate buffer size
#define NSEL 128     // min candidates selected by threshold

// ws layout (bytes)
#define WS_LOGITS_OFF 0         // 16384 f32
#define WS_CAND_OFF   65536     // 256 i32
#define WS_EXACT_OFF  66560     // 256 f32
#define WS_CNT_OFF    67584     // 1 i32 (+pad)
#define WS_TOPK_OFF   67600     // 64 i32
#define WS_PF_OFF     67856     // 64*512 f32
#define WS_WH_OFF     198928    // 512*256 u16 (bf16-hi of W1a, chunk-transposed+swizzled)
#define WS_WL_OFF     461072    // 512*256 u16 (bf16-lo)

__device__ __forceinline__ u16 bf16rne(float x) {
    union { float f; u32 u; } v; v.f = x;
    u32 r = (v.u + 0x7fffu + ((v.u >> 16) & 1u)) >> 16;
    return (u16)r;
}
__device__ __forceinline__ float bf16tof(u16 h) {
    union { float f; u32 u; } v; v.u = ((u32)h) << 16; return v.f;
}
__device__ __forceinline__ u32 f32sort(float x) {
    union { float f; u32 u; } v; v.f = x;
    return v.u ^ ((v.u & 0x80000000u) ? 0xFFFFFFFFu : 0x80000000u);
}

// -------- Kernel 0: split W1a into bf16 hi/lo, layout [kc][h][slot^swz], swz=(h>>1)&3 ----
// The XOR swizzle is baked into the GLOBAL layout so that the linear
// global_load_lds staging in k1 lands a bank-conflict-free LDS image (rule:
// swizzle both-sides-or-neither with global_load_lds).
__global__ __launch_bounds__(256) void k0_splitW(const float* __restrict__ W1,
                                                 u16* __restrict__ wh, u16* __restrict__ wl)
{
    const int kc = blockIdx.x;      // 16 chunks of K=32
    const int h  = threadIdx.x;     // 256
    const int swz = (h >> 1) & 3;   // frag-row swizzle
    u16 rh[32], rl[32];
#pragma unroll
    for (int kk = 0; kk < 32; ++kk) {
        float a = W1[(size_t)(kc * 32 + kk) * HH + h];
        u16 hi = bf16rne(a);
        float lo = a - bf16tof(hi);
        rh[kk] = hi; rl[kk] = bf16rne(lo);
    }
    const size_t base = (size_t)kc * 8192 + (size_t)h * 32;
#pragma unroll
    for (int q = 0; q < 4; ++q) {
        uint4 ph, pl;
        ph.x = (u32)rh[q*8+0] | ((u32)rh[q*8+1] << 16);
        ph.y = (u32)rh[q*8+2] | ((u32)rh[q*8+3] << 16);
        ph.z = (u32)rh[q*8+4] | ((u32)rh[q*8+5] << 16);
        ph.w = (u32)rh[q*8+6] | ((u32)rh[q*8+7] << 16);
        pl.x = (u32)rl[q*8+0] | ((u32)rl[q*8+1] << 16);
        pl.y = (u32)rl[q*8+2] | ((u32)rl[q*8+3] << 16);
        pl.z = (u32)rl[q*8+4] | ((u32)rl[q*8+5] << 16);
        pl.w = (u32)rl[q*8+6] | ((u32)rl[q*8+7] << 16);
        const int qs = (q ^ swz) * 8;
        *(uint4*)&wh[base + qs] = ph;
        *(uint4*)&wl[base + qs] = pl;
    }
}

// -------- Kernel 1: first-MLP logits via split-bf16 MFMA ----
// v2: 512 threads (8 waves = 2 j-halves x 4 h-quarters), M=128 per block,
// grid (i=128, r=8). XOR-swizzled fragment layout for conflict-free
// ds_read_b128. LDS 50KB -> 3 blocks/CU -> 24 waves/CU.
__global__ __launch_bounds__(512, 6) void k1_pair_mfma(
    const float* __restrict__ obj, const float* __restrict__ geo,
    const u16* __restrict__ wh, const u16* __restrict__ wl,
    const float* __restrict__ b1, const float* __restrict__ w2,
    float* __restrict__ logits_acc)
{
    const int i = blockIdx.x, r = blockIdx.y;
    const int tid = threadIdx.x;
    const int lane = tid & 63, wv = tid >> 6;
    const int l15 = lane & 15, quad = lane >> 4;
    const int mh = wv >> 2;                       // j-half (0..1)
    const int hq = wv & 3;                        // h-quarter (0..3)
    const int fsl = (quad ^ ((l15 >> 1) & 3)) * 8; // swizzled frag slot (u16)

    __shared__ float sObjI[DD];
    __shared__ __align__(16) u16 sAh[128 * 32], sAl[128 * 32];
    __shared__ __align__(16) u16 sBh[256 * 32], sBl[256 * 32];

    sObjI[tid] = obj[(size_t)(r * NN + i) * DD + tid];

    f32x4 acc[4][4];
#pragma unroll
    for (int mt = 0; mt < 4; ++mt)
#pragma unroll
        for (int nt = 0; nt < 4; ++nt) acc[mt][nt] = (f32x4){0.f, 0.f, 0.f, 0.f};

    const float* geoB = geo + (size_t)(r * NN + i) * NN * DD;
    const float* objJ = obj + (size_t)r * NN * DD;

    const int aj = tid >> 2;                      // j row this thread generates (0..127)
    const int ak = (tid & 3) * 8;                 // k offset within chunk
    const int asl = ((tid & 3) ^ ((aj >> 1) & 3)) * 8;  // swizzled A write slot

    for (int kc = 0; kc < 16; ++kc) {
        const int k0 = kc * 32;
        __syncthreads();
        {
            const char* gh = (const char*)(wh + (size_t)kc * 8192);
            const char* gl = (const char*)(wl + (size_t)kc * 8192);
#pragma unroll
            for (int p = 0; p < 2; ++p) {
                const int off = (wv * 2 + p) * 1024;   // bytes; wave-uniform
                __builtin_amdgcn_global_load_lds(
                    (const __attribute__((address_space(1))) u32*)(gh + off + lane * 16),
                    (__attribute__((address_space(3))) u32*)((char*)sBh + off), 16, 0, 0);
                __builtin_amdgcn_global_load_lds(
                    (const __attribute__((address_space(1))) u32*)(gl + off + lane * 16),
                    (__attribute__((address_space(3))) u32*)((char*)sBl + off), 16, 0, 0);
            }
        }
        {
            float4 g0 = *(const float4*)(geoB + (size_t)aj * DD + k0 + ak);
            float4 g1 = *(const float4*)(geoB + (size_t)aj * DD + k0 + ak + 4);
            float4 o0 = *(const float4*)(objJ + (size_t)aj * DD + k0 + ak);
            float4 o1 = *(const float4*)(objJ + (size_t)aj * DD + k0 + ak + 4);
            float a[8];
            a[0] = fmaf(sObjI[k0+ak+0], o0.x, g0.x);
            a[1] = fmaf(sObjI[k0+ak+1], o0.y, g0.y);
            a[2] = fmaf(sObjI[k0+ak+2], o0.z, g0.z);
            a[3] = fmaf(sObjI[k0+ak+3], o0.w, g0.w);
            a[4] = fmaf(sObjI[k0+ak+4], o1.x, g1.x);
            a[5] = fmaf(sObjI[k0+ak+5], o1.y, g1.y);
            a[6] = fmaf(sObjI[k0+ak+6], o1.z, g1.z);
            a[7] = fmaf(sObjI[k0+ak+7], o1.w, g1.w);
            u16 hs[8], ls[8];
#pragma unroll
            for (int q = 0; q < 8; ++q) {
                hs[q] = bf16rne(a[q]);
                ls[q] = bf16rne(a[q] - bf16tof(hs[q]));
            }
            uint4 ph, pl;
            ph.x = (u32)hs[0] | ((u32)hs[1] << 16); ph.y = (u32)hs[2] | ((u32)hs[3] << 16);
            ph.z = (u32)hs[4] | ((u32)hs[5] << 16); ph.w = (u32)hs[6] | ((u32)hs[7] << 16);
            pl.x = (u32)ls[0] | ((u32)ls[1] << 16); pl.y = (u32)ls[2] | ((u32)ls[3] << 16);
            pl.z = (u32)ls[4] | ((u32)ls[5] << 16); pl.w = (u32)ls[6] | ((u32)ls[7] << 16);
            *(uint4*)&sAh[aj * 32 + asl] = ph;
            *(uint4*)&sAl[aj * 32 + asl] = pl;
        }
        __syncthreads();
        bf16x8 Bh[4], Bl[4], Ah[4], Al[4];
#pragma unroll
        for (int nt = 0; nt < 4; ++nt) {
            const int row = hq * 64 + nt * 16 + l15;
            Bh[nt] = *(const bf16x8*)&sBh[row * 32 + fsl];
            Bl[nt] = *(const bf16x8*)&sBl[row * 32 + fsl];
        }
#pragma unroll
        for (int mt = 0; mt < 4; ++mt) {
            const int row = mh * 64 + mt * 16 + l15;
            Ah[mt] = *(const bf16x8*)&sAh[row * 32 + fsl];
            Al[mt] = *(const bf16x8*)&sAl[row * 32 + fsl];
        }
#pragma unroll
        for (int mt = 0; mt < 4; ++mt)
#pragma unroll
            for (int nt = 0; nt < 4; ++nt) {
                acc[mt][nt] = __builtin_amdgcn_mfma_f32_16x16x32_bf16(Ah[mt], Bh[nt], acc[mt][nt], 0, 0, 0);
                acc[mt][nt] = __builtin_amdgcn_mfma_f32_16x16x32_bf16(Ah[mt], Bl[nt], acc[mt][nt], 0, 0, 0);
                acc[mt][nt] = __builtin_amdgcn_mfma_f32_16x16x32_bf16(Al[mt], Bh[nt], acc[mt][nt], 0, 0, 0);
            }
    }
    float pr[4][4];
#pragma unroll
    for (int mt = 0; mt < 4; ++mt)
#pragma unroll
        for (int t = 0; t < 4; ++t) pr[mt][t] = 0.f;
#pragma unroll
    for (int nt = 0; nt < 4; ++nt) {
        const int h = hq * 64 + nt * 16 + l15;
        const float bb = b1[h], w = w2[h];
#pragma unroll
        for (int mt = 0; mt < 4; ++mt)
#pragma unroll
            for (int t = 0; t < 4; ++t)
                pr[mt][t] += fmaxf(acc[mt][nt][t] + bb, 0.f) * w;
    }
#pragma unroll
    for (int mt = 0; mt < 4; ++mt)
#pragma unroll
        for (int t = 0; t < 4; ++t) {
            float v = pr[mt][t];
            v += __shfl_xor(v, 1); v += __shfl_xor(v, 2);
            v += __shfl_xor(v, 4); v += __shfl_xor(v, 8);
            if (l15 == 0)
                atomicAdd(&logits_acc[i * NN + mh * 64 + mt * 16 + quad * 4 + t], v);
        }
}

// -------- Kernel 2: finalize o2o logits (out0) + radix-threshold candidate select ----
// v2: histogram replicated 16x (one copy per wave) to avoid hot-bin LDS-atomic
// serialization (logit exponents cluster into a few bins).
__global__ __launch_bounds__(1024) void k2_hist(
    const float* __restrict__ logits_acc, const float* __restrict__ mask,
    const float* __restrict__ b2a, float* __restrict__ out,
    int* __restrict__ cand, int* __restrict__ cnt_out)
{
    __shared__ u32 hist[16 * 256];   // 16 replicated copies
    __shared__ u32 sum1[256];
    __shared__ int sB1, sRem, sT16;
    __shared__ u32 sCnt;
    const int t = threadIdx.x;
    const int hb = (t >> 6) << 8;    // this wave's histogram copy base
    for (int b = t; b < 16 * 256; b += 1024) hist[b] = 0;
    if (t == 0) sCnt = 0;
    __syncthreads();
    const float bias = b2a[0];
    u32 skey[16];
#pragma unroll
    for (int e = 0; e < 16; ++e) {
        const int idx = e * 1024 + t;
        const float lg = logits_acc[idx] * 0.125f + bias;
        out[idx] = lg;                       // output 0
        u32 s = f32sort(lg);
        if (mask[idx] == 0.f) s = 0;         // excluded (prob forced to 0)
        skey[e] = s;
        atomicAdd(&hist[hb + (s >> 24)], 1u);
    }
    __syncthreads();
    if (t < 256) {
        u32 s = 0;
#pragma unroll
        for (int c = 0; c < 16; ++c) s += hist[c * 256 + t];
        sum1[t] = s;
    }
    __syncthreads();
    if (t == 0) {
        u32 cum = 0; int b = 255;
        for (; b > 0; --b) { u32 c = sum1[b]; if (cum + c >= (u32)NSEL) break; cum += c; }
        sB1 = b; sRem = NSEL - (int)cum;
    }
    __syncthreads();
    const int B1 = sB1;
    for (int b = t; b < 16 * 256; b += 1024) hist[b] = 0;
    __syncthreads();
#pragma unroll
    for (int e = 0; e < 16; ++e) {
        const u32 s = skey[e];
        if ((int)(s >> 24) == B1) atomicAdd(&hist[hb + ((s >> 16) & 0xFF)], 1u);
    }
    __syncthreads();
    if (t < 256) {
        u32 s = 0;
#pragma unroll
        for (int c = 0; c < 16; ++c) s += hist[c * 256 + t];
        sum1[t] = s;
    }
    __syncthreads();
    if (t == 0) {
        const int rem = sRem; u32 cum = 0; int b = 255;
        for (; b > 0; --b) { cum += sum1[b]; if ((int)cum >= rem) break; }
        sT16 = (B1 << 8) | b;
    }
    __syncthreads();
    const u32 T16 = (u32)sT16;
#pragma unroll
    for (int e = 0; e < 16; ++e) {
        const u32 s = skey[e];
        if (s != 0 && (s >> 16) >= T16) {
            const u32 pos = atomicAdd(&sCnt, 1u);
            if (pos < (u32)NCAND) cand[pos] = e * 1024 + t;
        }
    }
    __syncthreads();
    if (t == 0) *cnt_out = (int)(sCnt < (u32)NCAND ? sCnt : (u32)NCAND);
}

// -------- Kernel 5: exact fp32 recompute of candidate logits ----
__global__ __launch_bounds__(256) void k5_exact(
    const float* __restrict__ obj, const float* __restrict__ geo,
    const float* __restrict__ W1, const float* __restrict__ b1,
    const float* __restrict__ w2, const float* __restrict__ b2a,
    const int* __restrict__ cand, const int* __restrict__ cnt_ptr,
    float* __restrict__ exact)
{
    const int c = blockIdx.x;
    if (c >= *cnt_ptr) { if (threadIdx.x == 0) exact[c] = -1e30f; return; }
    const int idx = cand[c];
    const int i = idx >> 7, j = idx & 127;
    const int t = threadIdx.x;
    __shared__ float sA[RR][DD];
    __shared__ float sRed[4];
    for (int f = t; f < RR * DD; f += 256) {
        const int r = f >> 9, k = f & 511;
        sA[r][k] = fmaf(obj[(size_t)(r * NN + i) * DD + k],
                        obj[(size_t)(r * NN + j) * DD + k],
                        geo[((size_t)(r * NN + i) * NN + j) * DD + k]);
    }
    __syncthreads();
    float hv[RR];
#pragma unroll
    for (int r = 0; r < RR; ++r) hv[r] = 0.f;
#pragma unroll 4
    for (int k = 0; k < DD; ++k) {
        const float w = W1[(size_t)k * HH + t];
#pragma unroll
        for (int r = 0; r < RR; ++r) hv[r] = fmaf(sA[r][k], w, hv[r]);
    }
    const float bb = b1[t], wv2 = w2[t];
    float p = 0.f;
#pragma unroll
    for (int r = 0; r < RR; ++r) p += fmaxf(hv[r] + bb, 0.f) * wv2;
#pragma unroll
    for (int off = 1; off < 64; off <<= 1) p += __shfl_xor(p, off);
    if ((t & 63) == 0) sRed[t >> 6] = p;
    __syncthreads();
    if (t == 0) exact[c] = (sRed[0] + sRed[1] + sRed[2] + sRed[3]) * 0.125f + b2a[0];
}

// -------- Kernel 2b: bitonic re-rank of candidates by exact prob -> top-64 (out2) ----
__global__ __launch_bounds__(256) void k_sort(
    const float* __restrict__ exact, const int* __restrict__ cand,
    float* __restrict__ out, int* __restrict__ topk)
{
    __shared__ u64 sKey[NCAND];
    const int t = threadIdx.x;
    {
        const float lg = exact[t];
        u32 ps = 0; u32 idx = 0x7FFFFFFFu;
        if (lg > -1e29f) {
            const float p = 1.f / (1.f + expf(-lg));
            ps = f32sort(p);
            idx = (u32)cand[t];
        }
        sKey[t] = ((u64)ps << 32) | (u64)(0xFFFFFFFFu - idx);
    }
    for (int k = 2; k <= NCAND; k <<= 1)
        for (int j = k >> 1; j > 0; j >>= 1) {
            __syncthreads();
            const int ixj = t ^ j;
            if (ixj > t) {
                const u64 a = sKey[t], b = sKey[ixj];
                if (((t & k) == 0) ? (a < b) : (a > b)) { sKey[t] = b; sKey[ixj] = a; }
            }
        }
    __syncthreads();
    if (t < KTOP) {
        const u32 idx = 0xFFFFFFFFu - (u32)(sKey[t] & 0xFFFFFFFFull);
        topk[t] = (int)idx;
        out[20480 + t] = (float)idx;      // output 2
    }
}

// -------- Kernel 3: gather averaged pair features for final top-64 ----
__global__ __launch_bounds__(256) void k3_gather(
    const float* __restrict__ obj, const float* __restrict__ geo,
    const int* __restrict__ ws_topk, float* __restrict__ pf)
{
    const int tix = blockIdx.x;            // 0..63
    const int idx = ws_topk[tix];
    const int i = idx >> 7, j = idx & 127;
    for (int dd = threadIdx.x; dd < DD; dd += 256) {
        float s = 0.f;
#pragma unroll
        for (int r = 0; r < RR; ++r) {
            const float oi = obj[(size_t)(r * NN + i) * DD + dd];
            const float oj = obj[(size_t)(r * NN + j) * DD + dd];
            const float g  = geo[((size_t)(r * NN + i) * NN + j) * DD + dd];
            s += oi * oj + g;
        }
        pf[tix * DD + dd] = s * 0.125f;
    }
}

// -------- Kernel 4: fused p2p MLP, one block per row a, full K, direct write ----
__global__ __launch_bounds__(256) void k4_p2p(
    const float* __restrict__ pf, const float* __restrict__ W1,
    const float* __restrict__ b1, const float* __restrict__ w2,
    const float* __restrict__ b2, float* __restrict__ out)
{
    const int a = blockIdx.x;
    const int tid = threadIdx.x;
    const int tx = tid & 15, ty = tid >> 4;

    __shared__ float sPfA[DD];
    __shared__ __align__(16) float sA[32][68];
    __shared__ __align__(16) float sB[32][HH];

    const float* pfA = pf + (size_t)a * DD;
    for (int t = tid; t < DD; t += 256) sPfA[t] = pfA[t];

    float acc[4][16];
#pragma unroll
    for (int m = 0; m < 4; ++m)
#pragma unroll
        for (int n = 0; n < 16; ++n) acc[m][n] = 0.f;

    for (int kc = 0; kc < 16; ++kc) {
        const int k0 = kc * 32;
        __syncthreads();
#pragma unroll
        for (int p = 0; p < 8; ++p) {
            const int f = tid + p * 256;
            const int kk = f >> 6, c = (f & 63) << 2;
            *(float4*)&sB[kk][c] = *(const float4*)&W1[(size_t)(k0 + kk) * HH + c];
        }
#pragma unroll
        for (int p = 0; p < 2; ++p) {
            const int f = tid + p * 256;
            const int j = f >> 3, kk = (f & 7) << 2;
            float4 o = *(const float4*)(pf + (size_t)j * DD + k0 + kk);
            sA[kk + 0][j] = sPfA[k0 + kk + 0] * o.x;
            sA[kk + 1][j] = sPfA[k0 + kk + 1] * o.y;
            sA[kk + 2][j] = sPfA[k0 + kk + 2] * o.z;
            sA[kk + 3][j] = sPfA[k0 + kk + 3] * o.w;
        }
        __syncthreads();
#pragma unroll 8
        for (int kk = 0; kk < 32; ++kk) {
            float4 a4 = *(const float4*)&sA[kk][ty << 2];
            float av[4] = {a4.x, a4.y, a4.z, a4.w};
#pragma unroll
            for (int n4 = 0; n4 < 4; ++n4) {
                float4 b4 = *(const float4*)&sB[kk][(n4 << 6) + (tx << 2)];
                float bv[4] = {b4.x, b4.y, b4.z, b4.w};
#pragma unroll
                for (int m = 0; m < 4; ++m)
#pragma unroll
                    for (int c = 0; c < 4; ++c)
                        acc[m][(n4 << 2) + c] = fmaf(av[m], bv[c], acc[m][(n4 << 2) + c]);
            }
        }
    }
    const float b20 = b2[0];
    float pr[4] = {0.f, 0.f, 0.f, 0.f};
#pragma unroll
    for (int n4 = 0; n4 < 4; ++n4)
#pragma unroll
        for (int c = 0; c < 4; ++c) {
            const int h = (n4 << 6) + (tx << 2) + c;
            const float bb = b1[h], w = w2[h];
#pragma unroll
            for (int m = 0; m < 4; ++m)
                pr[m] += fmaxf(acc[m][(n4 << 2) + c] + bb, 0.f) * w;
        }
#pragma unroll
    for (int m = 0; m < 4; ++m) {
        pr[m] += __shfl_xor(pr[m], 1); pr[m] += __shfl_xor(pr[m], 2);
        pr[m] += __shfl_xor(pr[m], 4); pr[m] += __shfl_xor(pr[m], 8);
        if (tx == 0)
            out[16384 + a * 64 + (ty << 2) + m] = pr[m] + b20;  // output 1
    }
}

extern "C" void kernel_launch(void* const* d_in, const int* in_sizes, int n_in,
                              void* d_out, int out_size, void* d_ws, size_t ws_size,
                              hipStream_t stream) {
    const float* obj  = (const float*)d_in[0];
    const float* geo  = (const float*)d_in[1];
    const float* mask = (const float*)d_in[2];
    const float* w1a  = (const float*)d_in[3];
    const float* b1a  = (const float*)d_in[4];
    const float* w2a  = (const float*)d_in[5];
    const float* b2a  = (const float*)d_in[6];
    const float* w1b  = (const float*)d_in[7];
    const float* b1b  = (const float*)d_in[8];
    const float* w2b  = (const float*)d_in[9];
    const float* b2b  = (const float*)d_in[10];
    float* out = (float*)d_out;

    char* ws = (char*)d_ws;
    float* ws_logits = (float*)(ws + WS_LOGITS_OFF);
    int*   ws_cand   = (int*)  (ws + WS_CAND_OFF);
    float* ws_exact  = (float*)(ws + WS_EXACT_OFF);
    int*   ws_cnt    = (int*)  (ws + WS_CNT_OFF);
    int*   ws_topk   = (int*)  (ws + WS_TOPK_OFF);
    float* ws_pf     = (float*)(ws + WS_PF_OFF);
    u16*   ws_wh     = (u16*)  (ws + WS_WH_OFF);
    u16*   ws_wl     = (u16*)  (ws + WS_WL_OFF);

    hipMemsetAsync(ws_logits, 0, 16384 * sizeof(float), stream);

    k0_splitW<<<16, 256, 0, stream>>>(w1a, ws_wh, ws_wl);
    k1_pair_mfma<<<dim3(NN, RR), 512, 0, stream>>>(obj, geo, ws_wh, ws_wl, b1a, w2a, ws_logits);
    k2_hist<<<1, 1024, 0, stream>>>(ws_logits, mask, b2a, out, ws_cand, ws_cnt);
    k5_exact<<<NCAND, 256, 0, stream>>>(obj, geo, w1a, b1a, w2a, b2a, ws_cand, ws_cnt, ws_exact);
    k_sort<<<1, 256, 0, stream>>>(ws_exact, ws_cand, out, ws_topk);
    k3_gather<<<KTOP, 256, 0, stream>>>(obj, geo, ws_topk, ws_pf);
    k4_p2p<<<KTOP, 256, 0, stream>>>(ws_pf, w1b, b1b, w2b, b2b, out);
}

// Round 2
// 636.751 us; speedup vs baseline: 2.0950x; 2.0950x over previous
//
#include <hip/hip_runtime.h>
#include <math.h>

typedef unsigned int u32;
typedef unsigned long long u64;
typedef unsigned short u16;
typedef short bf16x8 __attribute__((ext_vector_type(8)));
typedef float f32x4 __attribute__((ext_vector_type(4)));

#define RR 8
#define NN 128
#define DD 512
#define HH 256
#define KTOP 64
#define NCAND 256    // candidate buffer size
#define NSEL 128     // min candidates selected by threshold

// ws layout (bytes)
#define WS_LOGITS_OFF 0         // 16384 f32
#define WS_CAND_OFF   65536     // 256 i32
#define WS_EXACT_OFF  66560     // 256 f32
#define WS_CNT_OFF    67584     // 1 i32 (+pad)
#define WS_TOPK_OFF   67600     // 64 i32
#define WS_PF_OFF     67856     // 64*512 f32
#define WS_WH_OFF     198928    // 512*256 u16 (bf16-hi of W1a, chunk-transposed+swizzled)
#define WS_WL_OFF     461072    // 512*256 u16 (bf16-lo)

__device__ __forceinline__ u16 bf16rne(float x) {
    union { float f; u32 u; } v; v.f = x;
    u32 r = (v.u + 0x7fffu + ((v.u >> 16) & 1u)) >> 16;
    return (u16)r;
}
__device__ __forceinline__ float bf16tof(u16 h) {
    union { float f; u32 u; } v; v.u = ((u32)h) << 16; return v.f;
}
__device__ __forceinline__ u32 f32sort(float x) {
    union { float f; u32 u; } v; v.f = x;
    return v.u ^ ((v.u & 0x80000000u) ? 0xFFFFFFFFu : 0x80000000u);
}

// -------- Kernel 0: split W1a into bf16 hi/lo, layout [kc][h][slot^swz], swz=(h>>1)&3 ----
// XOR swizzle baked into the GLOBAL layout so linear global_load_lds staging in
// k1 lands a bank-conflict-free LDS image (swizzle both-sides-or-neither rule).
// HW-verified round 1: SQ_LDS_BANK_CONFLICT == 0 with this layout.
__global__ __launch_bounds__(256) void k0_splitW(const float* __restrict__ W1,
                                                 u16* __restrict__ wh, u16* __restrict__ wl)
{
    const int kc = blockIdx.x;      // 16 chunks of K=32
    const int h  = threadIdx.x;     // 256
    const int swz = (h >> 1) & 3;   // frag-row swizzle
    u16 rh[32], rl[32];
#pragma unroll
    for (int kk = 0; kk < 32; ++kk) {
        float a = W1[(size_t)(kc * 32 + kk) * HH + h];
        u16 hi = bf16rne(a);
        float lo = a - bf16tof(hi);
        rh[kk] = hi; rl[kk] = bf16rne(lo);
    }
    const size_t base = (size_t)kc * 8192 + (size_t)h * 32;
#pragma unroll
    for (int q = 0; q < 4; ++q) {
        uint4 ph, pl;
        ph.x = (u32)rh[q*8+0] | ((u32)rh[q*8+1] << 16);
        ph.y = (u32)rh[q*8+2] | ((u32)rh[q*8+3] << 16);
        ph.z = (u32)rh[q*8+4] | ((u32)rh[q*8+5] << 16);
        ph.w = (u32)rh[q*8+6] | ((u32)rh[q*8+7] << 16);
        pl.x = (u32)rl[q*8+0] | ((u32)rl[q*8+1] << 16);
        pl.y = (u32)rl[q*8+2] | ((u32)rl[q*8+3] << 16);
        pl.z = (u32)rl[q*8+4] | ((u32)rl[q*8+5] << 16);
        pl.w = (u32)rl[q*8+6] | ((u32)rl[q*8+7] << 16);
        const int qs = (q ^ swz) * 8;
        *(uint4*)&wh[base + qs] = ph;
        *(uint4*)&wl[base + qs] = pl;
    }
}

// -------- Kernel 1: first-MLP logits via split-bf16 MFMA ----
// Round-0 structure (256 thr, 4 waves, M=64 tile, grid (2,128,8)) — VGPR ~76,
// no launch_bounds register pressure (round-1 lesson: forcing 6 w/EU spilled
// acc to scratch, 2.1 GB writes). Swizzled fragment addressing (fsl/asl)
// eliminates the 8.4M LDS bank conflicts measured in round 0.
__global__ __launch_bounds__(256, 2) void k1_pair_mfma(
    const float* __restrict__ obj, const float* __restrict__ geo,
    const u16* __restrict__ wh, const u16* __restrict__ wl,
    const float* __restrict__ b1, const float* __restrict__ w2,
    float* __restrict__ logits_acc)
{
    const int jb = blockIdx.x, i = blockIdx.y, r = blockIdx.z;
    const int j0 = jb * 64;
    const int tid = threadIdx.x;
    const int lane = tid & 63, wv = tid >> 6;
    const int l15 = lane & 15, quad = lane >> 4;
    const int fsl = (quad ^ ((l15 >> 1) & 3)) * 8;   // swizzled frag slot (u16)

    __shared__ float sObjI[DD];
    __shared__ __align__(16) u16 sAh[64 * 32], sAl[64 * 32];
    __shared__ __align__(16) u16 sBh[256 * 32], sBl[256 * 32];

    const float* objI = obj + (size_t)(r * NN + i) * DD;
    for (int t = tid; t < DD; t += 256) sObjI[t] = objI[t];

    f32x4 acc[4][4];
#pragma unroll
    for (int mt = 0; mt < 4; ++mt)
#pragma unroll
        for (int nt = 0; nt < 4; ++nt) acc[mt][nt] = (f32x4){0.f, 0.f, 0.f, 0.f};

    const float* geoB = geo + ((size_t)(r * NN + i) * NN + j0) * DD;
    const float* objJ = obj + (size_t)(r * NN + j0) * DD;

    const int aj = tid >> 2;            // j row this thread generates (0..63)
    const int ak = (tid & 3) * 8;       // k offset within chunk (0,8,16,24)
    const int asl = ((tid & 3) ^ ((aj >> 1) & 3)) * 8;  // swizzled A write slot

    for (int kc = 0; kc < 16; ++kc) {
        const int k0 = kc * 32;
        __syncthreads();
        {
            const char* gh = (const char*)(wh + (size_t)kc * 8192);
            const char* gl = (const char*)(wl + (size_t)kc * 8192);
#pragma unroll
            for (int p = 0; p < 4; ++p) {
                const int off = (wv * 4 + p) * 1024;   // bytes; wave-uniform
                __builtin_amdgcn_global_load_lds(
                    (const __attribute__((address_space(1))) u32*)(gh + off + lane * 16),
                    (__attribute__((address_space(3))) u32*)((char*)sBh + off), 16, 0, 0);
                __builtin_amdgcn_global_load_lds(
                    (const __attribute__((address_space(1))) u32*)(gl + off + lane * 16),
                    (__attribute__((address_space(3))) u32*)((char*)sBl + off), 16, 0, 0);
            }
        }
        {
            float4 g0 = *(const float4*)(geoB + (size_t)aj * DD + k0 + ak);
            float4 g1 = *(const float4*)(geoB + (size_t)aj * DD + k0 + ak + 4);
            float4 o0 = *(const float4*)(objJ + (size_t)aj * DD + k0 + ak);
            float4 o1 = *(const float4*)(objJ + (size_t)aj * DD + k0 + ak + 4);
            float a[8];
            a[0] = fmaf(sObjI[k0+ak+0], o0.x, g0.x);
            a[1] = fmaf(sObjI[k0+ak+1], o0.y, g0.y);
            a[2] = fmaf(sObjI[k0+ak+2], o0.z, g0.z);
            a[3] = fmaf(sObjI[k0+ak+3], o0.w, g0.w);
            a[4] = fmaf(sObjI[k0+ak+4], o1.x, g1.x);
            a[5] = fmaf(sObjI[k0+ak+5], o1.y, g1.y);
            a[6] = fmaf(sObjI[k0+ak+6], o1.z, g1.z);
            a[7] = fmaf(sObjI[k0+ak+7], o1.w, g1.w);
            u16 hs[8], ls[8];
#pragma unroll
            for (int q = 0; q < 8; ++q) {
                hs[q] = bf16rne(a[q]);
                ls[q] = bf16rne(a[q] - bf16tof(hs[q]));
            }
            uint4 ph, pl;
            ph.x = (u32)hs[0] | ((u32)hs[1] << 16); ph.y = (u32)hs[2] | ((u32)hs[3] << 16);
            ph.z = (u32)hs[4] | ((u32)hs[5] << 16); ph.w = (u32)hs[6] | ((u32)hs[7] << 16);
            pl.x = (u32)ls[0] | ((u32)ls[1] << 16); pl.y = (u32)ls[2] | ((u32)ls[3] << 16);
            pl.z = (u32)ls[4] | ((u32)ls[5] << 16); pl.w = (u32)ls[6] | ((u32)ls[7] << 16);
            *(uint4*)&sAh[aj * 32 + asl] = ph;
            *(uint4*)&sAl[aj * 32 + asl] = pl;
        }
        __syncthreads();
        bf16x8 Bh[4], Bl[4], Ah[4], Al[4];
#pragma unroll
        for (int nt = 0; nt < 4; ++nt) {
            const int row = wv * 64 + nt * 16 + l15;
            Bh[nt] = *(const bf16x8*)&sBh[row * 32 + fsl];
            Bl[nt] = *(const bf16x8*)&sBl[row * 32 + fsl];
        }
#pragma unroll
        for (int mt = 0; mt < 4; ++mt) {
            const int row = mt * 16 + l15;
            Ah[mt] = *(const bf16x8*)&sAh[row * 32 + fsl];
            Al[mt] = *(const bf16x8*)&sAl[row * 32 + fsl];
        }
#pragma unroll
        for (int mt = 0; mt < 4; ++mt)
#pragma unroll
            for (int nt = 0; nt < 4; ++nt) {
                acc[mt][nt] = __builtin_amdgcn_mfma_f32_16x16x32_bf16(Ah[mt], Bh[nt], acc[mt][nt], 0, 0, 0);
                acc[mt][nt] = __builtin_amdgcn_mfma_f32_16x16x32_bf16(Ah[mt], Bl[nt], acc[mt][nt], 0, 0, 0);
                acc[mt][nt] = __builtin_amdgcn_mfma_f32_16x16x32_bf16(Al[mt], Bh[nt], acc[mt][nt], 0, 0, 0);
            }
    }
    float pr[4][4];
#pragma unroll
    for (int mt = 0; mt < 4; ++mt)
#pragma unroll
        for (int t = 0; t < 4; ++t) pr[mt][t] = 0.f;
#pragma unroll
    for (int nt = 0; nt < 4; ++nt) {
        const int h = wv * 64 + nt * 16 + l15;
        const float bb = b1[h], w = w2[h];
#pragma unroll
        for (int mt = 0; mt < 4; ++mt)
#pragma unroll
            for (int t = 0; t < 4; ++t)
                pr[mt][t] += fmaxf(acc[mt][nt][t] + bb, 0.f) * w;
    }
#pragma unroll
    for (int mt = 0; mt < 4; ++mt)
#pragma unroll
        for (int t = 0; t < 4; ++t) {
            float v = pr[mt][t];
            v += __shfl_xor(v, 1); v += __shfl_xor(v, 2);
            v += __shfl_xor(v, 4); v += __shfl_xor(v, 8);
            if (l15 == 0)
                atomicAdd(&logits_acc[i * NN + j0 + mt * 16 + quad * 4 + t], v);
        }
}

// -------- Kernel 2: finalize o2o logits (out0) + radix-threshold candidate select ----
// Histogram replicated 16x (one copy per wave) to avoid hot-bin LDS-atomic
// serialization (logit exponents cluster into a few bins).
__global__ __launch_bounds__(1024) void k2_hist(
    const float* __restrict__ logits_acc, const float* __restrict__ mask,
    const float* __restrict__ b2a, float* __restrict__ out,
    int* __restrict__ cand, int* __restrict__ cnt_out)
{
    __shared__ u32 hist[16 * 256];   // 16 replicated copies
    __shared__ u32 sum1[256];
    __shared__ int sB1, sRem, sT16;
    __shared__ u32 sCnt;
    const int t = threadIdx.x;
    const int hb = (t >> 6) << 8;    // this wave's histogram copy base
    for (int b = t; b < 16 * 256; b += 1024) hist[b] = 0;
    if (t == 0) sCnt = 0;
    __syncthreads();
    const float bias = b2a[0];
    u32 skey[16];
#pragma unroll
    for (int e = 0; e < 16; ++e) {
        const int idx = e * 1024 + t;
        const float lg = logits_acc[idx] * 0.125f + bias;
        out[idx] = lg;                       // output 0
        u32 s = f32sort(lg);
        if (mask[idx] == 0.f) s = 0;         // excluded (prob forced to 0)
        skey[e] = s;
        atomicAdd(&hist[hb + (s >> 24)], 1u);
    }
    __syncthreads();
    if (t < 256) {
        u32 s = 0;
#pragma unroll
        for (int c = 0; c < 16; ++c) s += hist[c * 256 + t];
        sum1[t] = s;
    }
    __syncthreads();
    if (t == 0) {
        u32 cum = 0; int b = 255;
        for (; b > 0; --b) { u32 c = sum1[b]; if (cum + c >= (u32)NSEL) break; cum += c; }
        sB1 = b; sRem = NSEL - (int)cum;
    }
    __syncthreads();
    const int B1 = sB1;
    for (int b = t; b < 16 * 256; b += 1024) hist[b] = 0;
    __syncthreads();
#pragma unroll
    for (int e = 0; e < 16; ++e) {
        const u32 s = skey[e];
        if ((int)(s >> 24) == B1) atomicAdd(&hist[hb + ((s >> 16) & 0xFF)], 1u);
    }
    __syncthreads();
    if (t < 256) {
        u32 s = 0;
#pragma unroll
        for (int c = 0; c < 16; ++c) s += hist[c * 256 + t];
        sum1[t] = s;
    }
    __syncthreads();
    if (t == 0) {
        const int rem = sRem; u32 cum = 0; int b = 255;
        for (; b > 0; --b) { cum += sum1[b]; if ((int)cum >= rem) break; }
        sT16 = (B1 << 8) | b;
    }
    __syncthreads();
    const u32 T16 = (u32)sT16;
#pragma unroll
    for (int e = 0; e < 16; ++e) {
        const u32 s = skey[e];
        if (s != 0 && (s >> 16) >= T16) {
            const u32 pos = atomicAdd(&sCnt, 1u);
            if (pos < (u32)NCAND) cand[pos] = e * 1024 + t;
        }
    }
    __syncthreads();
    if (t == 0) *cnt_out = (int)(sCnt < (u32)NCAND ? sCnt : (u32)NCAND);
}

// -------- Kernel 5: exact fp32 recompute of candidate logits ----
__global__ __launch_bounds__(256) void k5_exact(
    const float* __restrict__ obj, const float* __restrict__ geo,
    const float* __restrict__ W1, const float* __restrict__ b1,
    const float* __restrict__ w2, const float* __restrict__ b2a,
    const int* __restrict__ cand, const int* __restrict__ cnt_ptr,
    float* __restrict__ exact)
{
    const int c = blockIdx.x;
    if (c >= *cnt_ptr) { if (threadIdx.x == 0) exact[c] = -1e30f; return; }
    const int idx = cand[c];
    const int i = idx >> 7, j = idx & 127;
    const int t = threadIdx.x;
    __shared__ float sA[RR][DD];
    __shared__ float sRed[4];
    for (int f = t; f < RR * DD; f += 256) {
        const int r = f >> 9, k = f & 511;
        sA[r][k] = fmaf(obj[(size_t)(r * NN + i) * DD + k],
                        obj[(size_t)(r * NN + j) * DD + k],
                        geo[((size_t)(r * NN + i) * NN + j) * DD + k]);
    }
    __syncthreads();
    float hv[RR];
#pragma unroll
    for (int r = 0; r < RR; ++r) hv[r] = 0.f;
#pragma unroll 4
    for (int k = 0; k < DD; ++k) {
        const float w = W1[(size_t)k * HH + t];
#pragma unroll
        for (int r = 0; r < RR; ++r) hv[r] = fmaf(sA[r][k], w, hv[r]);
    }
    const float bb = b1[t], wv2 = w2[t];
    float p = 0.f;
#pragma unroll
    for (int r = 0; r < RR; ++r) p += fmaxf(hv[r] + bb, 0.f) * wv2;
#pragma unroll
    for (int off = 1; off < 64; off <<= 1) p += __shfl_xor(p, off);
    if ((t & 63) == 0) sRed[t >> 6] = p;
    __syncthreads();
    if (t == 0) exact[c] = (sRed[0] + sRed[1] + sRed[2] + sRed[3]) * 0.125f + b2a[0];
}

// -------- Kernel 2b: bitonic re-rank of candidates by exact prob -> top-64 (out2) ----
__global__ __launch_bounds__(256) void k_sort(
    const float* __restrict__ exact, const int* __restrict__ cand,
    float* __restrict__ out, int* __restrict__ topk)
{
    __shared__ u64 sKey[NCAND];
    const int t = threadIdx.x;
    {
        const float lg = exact[t];
        u32 ps = 0; u32 idx = 0x7FFFFFFFu;
        if (lg > -1e29f) {
            const float p = 1.f / (1.f + expf(-lg));
            ps = f32sort(p);
            idx = (u32)cand[t];
        }
        sKey[t] = ((u64)ps << 32) | (u64)(0xFFFFFFFFu - idx);
    }
    for (int k = 2; k <= NCAND; k <<= 1)
        for (int j = k >> 1; j > 0; j >>= 1) {
            __syncthreads();
            const int ixj = t ^ j;
            if (ixj > t) {
                const u64 a = sKey[t], b = sKey[ixj];
                if (((t & k) == 0) ? (a < b) : (a > b)) { sKey[t] = b; sKey[ixj] = a; }
            }
        }
    __syncthreads();
    if (t < KTOP) {
        const u32 idx = 0xFFFFFFFFu - (u32)(sKey[t] & 0xFFFFFFFFull);
        topk[t] = (int)idx;
        out[20480 + t] = (float)idx;      // output 2
    }
}

// -------- Kernel 3: gather averaged pair features for final top-64 ----
__global__ __launch_bounds__(256) void k3_gather(
    const float* __restrict__ obj, const float* __restrict__ geo,
    const int* __restrict__ ws_topk, float* __restrict__ pf)
{
    const int tix = blockIdx.x;            // 0..63
    const int idx = ws_topk[tix];
    const int i = idx >> 7, j = idx & 127;
    for (int dd = threadIdx.x; dd < DD; dd += 256) {
        float s = 0.f;
#pragma unroll
        for (int r = 0; r < RR; ++r) {
            const float oi = obj[(size_t)(r * NN + i) * DD + dd];
            const float oj = obj[(size_t)(r * NN + j) * DD + dd];
            const float g  = geo[((size_t)(r * NN + i) * NN + j) * DD + dd];
            s += oi * oj + g;
        }
        pf[tix * DD + dd] = s * 0.125f;
    }
}

// -------- Kernel 4: fused p2p MLP, one block per row a, full K, direct write ----
__global__ __launch_bounds__(256) void k4_p2p(
    const float* __restrict__ pf, const float* __restrict__ W1,
    const float* __restrict__ b1, const float* __restrict__ w2,
    const float* __restrict__ b2, float* __restrict__ out)
{
    const int a = blockIdx.x;
    const int tid = threadIdx.x;
    const int tx = tid & 15, ty = tid >> 4;

    __shared__ float sPfA[DD];
    __shared__ __align__(16) float sA[32][68];
    __shared__ __align__(16) float sB[32][HH];

    const float* pfA = pf + (size_t)a * DD;
    for (int t = tid; t < DD; t += 256) sPfA[t] = pfA[t];

    float acc[4][16];
#pragma unroll
    for (int m = 0; m < 4; ++m)
#pragma unroll
        for (int n = 0; n < 16; ++n) acc[m][n] = 0.f;

    for (int kc = 0; kc < 16; ++kc) {
        const int k0 = kc * 32;
        __syncthreads();
#pragma unroll
        for (int p = 0; p < 8; ++p) {
            const int f = tid + p * 256;
            const int kk = f >> 6, c = (f & 63) << 2;
            *(float4*)&sB[kk][c] = *(const float4*)&W1[(size_t)(k0 + kk) * HH + c];
        }
#pragma unroll
        for (int p = 0; p < 2; ++p) {
            const int f = tid + p * 256;
            const int j = f >> 3, kk = (f & 7) << 2;
            float4 o = *(const float4*)(pf + (size_t)j * DD + k0 + kk);
            sA[kk + 0][j] = sPfA[k0 + kk + 0] * o.x;
            sA[kk + 1][j] = sPfA[k0 + kk + 1] * o.y;
            sA[kk + 2][j] = sPfA[k0 + kk + 2] * o.z;
            sA[kk + 3][j] = sPfA[k0 + kk + 3] * o.w;
        }
        __syncthreads();
#pragma unroll 8
        for (int kk = 0; kk < 32; ++kk) {
            float4 a4 = *(const float4*)&sA[kk][ty << 2];
            float av[4] = {a4.x, a4.y, a4.z, a4.w};
#pragma unroll
            for (int n4 = 0; n4 < 4; ++n4) {
                float4 b4 = *(const float4*)&sB[kk][(n4 << 6) + (tx << 2)];
                float bv[4] = {b4.x, b4.y, b4.z, b4.w};
#pragma unroll
                for (int m = 0; m < 4; ++m)
#pragma unroll
                    for (int c = 0; c < 4; ++c)
                        acc[m][(n4 << 2) + c] = fmaf(av[m], bv[c], acc[m][(n4 << 2) + c]);
            }
        }
    }
    const float b20 = b2[0];
    float pr[4] = {0.f, 0.f, 0.f, 0.f};
#pragma unroll
    for (int n4 = 0; n4 < 4; ++n4)
#pragma unroll
        for (int c = 0; c < 4; ++c) {
            const int h = (n4 << 6) + (tx << 2) + c;
            const float bb = b1[h], w = w2[h];
#pragma unroll
            for (int m = 0; m < 4; ++m)
                pr[m] += fmaxf(acc[m][(n4 << 2) + c] + bb, 0.f) * w;
        }
#pragma unroll
    for (int m = 0; m < 4; ++m) {
        pr[m] += __shfl_xor(pr[m], 1); pr[m] += __shfl_xor(pr[m], 2);
        pr[m] += __shfl_xor(pr[m], 4); pr[m] += __shfl_xor(pr[m], 8);
        if (tx == 0)
            out[16384 + a * 64 + (ty << 2) + m] = pr[m] + b20;  // output 1
    }
}

extern "C" void kernel_launch(void* const* d_in, const int* in_sizes, int n_in,
                              void* d_out, int out_size, void* d_ws, size_t ws_size,
                              hipStream_t stream) {
    const float* obj  = (const float*)d_in[0];
    const float* geo  = (const float*)d_in[1];
    const float* mask = (const float*)d_in[2];
    const float* w1a  = (const float*)d_in[3];
    const float* b1a  = (const float*)d_in[4];
    const float* w2a  = (const float*)d_in[5];
    const float* b2a  = (const float*)d_in[6];
    const float* w1b  = (const float*)d_in[7];
    const float* b1b  = (const float*)d_in[8];
    const float* w2b  = (const float*)d_in[9];
    const float* b2b  = (const float*)d_in[10];
    float* out = (float*)d_out;

    char* ws = (char*)d_ws;
    float* ws_logits = (float*)(ws + WS_LOGITS_OFF);
    int*   ws_cand   = (int*)  (ws + WS_CAND_OFF);
    float* ws_exact  = (float*)(ws + WS_EXACT_OFF);
    int*   ws_cnt    = (int*)  (ws + WS_CNT_OFF);
    int*   ws_topk   = (int*)  (ws + WS_TOPK_OFF);
    float* ws_pf     = (float*)(ws + WS_PF_OFF);
    u16*   ws_wh     = (u16*)  (ws + WS_WH_OFF);
    u16*   ws_wl     = (u16*)  (ws + WS_WL_OFF);

    hipMemsetAsync(ws_logits, 0, 16384 * sizeof(float), stream);

    k0_splitW<<<16, 256, 0, stream>>>(w1a, ws_wh, ws_wl);
    k1_pair_mfma<<<dim3(2, NN, RR), 256, 0, stream>>>(obj, geo, ws_wh, ws_wl, b1a, w2a, ws_logits);
    k2_hist<<<1, 1024, 0, stream>>>(ws_logits, mask, b2a, out, ws_cand, ws_cnt);
    k5_exact<<<NCAND, 256, 0, stream>>>(obj, geo, w1a, b1a, w2a, b2a, ws_cand, ws_cnt, ws_exact);
    k_sort<<<1, 256, 0, stream>>>(ws_exact, ws_cand, out, ws_topk);
    k3_gather<<<KTOP, 256, 0, stream>>>(obj, geo, ws_topk, ws_pf);
    k4_p2p<<<KTOP, 256, 0, stream>>>(ws_pf, w1b, b1b, w2b, b2b, out);
}

// Round 3
// 635.425 us; speedup vs baseline: 2.0994x; 1.0021x over previous
//
#include <hip/hip_runtime.h>
#include <math.h>

typedef unsigned int u32;
typedef unsigned long long u64;
typedef unsigned short u16;
typedef short bf16x8 __attribute__((ext_vector_type(8)));
typedef float f32x4 __attribute__((ext_vector_type(4)));

#define RR 8
#define NN 128
#define DD 512
#define HH 256
#define KTOP 64
#define NCAND 256    // candidate buffer size
#define NSEL 128     // min candidates selected by threshold

// ws layout (bytes)
#define WS_LOGITS_OFF 0         // 16384 f32
#define WS_CAND_OFF   65536     // 256 i32
#define WS_EXACT_OFF  66560     // 256 f32
#define WS_CNT_OFF    67584     // 1 i32 (+pad)
#define WS_TOPK_OFF   67600     // 64 i32
#define WS_PF_OFF     67856     // 64*512 f32
#define WS_WH_OFF     198928    // 512*256 u16 (bf16-hi of W1a, chunk-transposed+swizzled)
#define WS_WL_OFF     461072    // 512*256 u16 (bf16-lo)

__device__ __forceinline__ u16 bf16rne(float x) {
    union { float f; u32 u; } v; v.f = x;
    u32 r = (v.u + 0x7fffu + ((v.u >> 16) & 1u)) >> 16;
    return (u16)r;
}
__device__ __forceinline__ float bf16tof(u16 h) {
    union { float f; u32 u; } v; v.u = ((u32)h) << 16; return v.f;
}
__device__ __forceinline__ u32 f32sort(float x) {
    union { float f; u32 u; } v; v.f = x;
    return v.u ^ ((v.u & 0x80000000u) ? 0xFFFFFFFFu : 0x80000000u);
}

// -------- Kernel 0: split W1a into bf16 hi/lo, layout [kc][h][slot^swz], swz=(h>>1)&3 ----
// XOR swizzle baked into the GLOBAL layout so linear global_load_lds staging in
// k1 lands a bank-conflict-free LDS image. HW-verified: SQ_LDS_BANK_CONFLICT == 0.
__global__ __launch_bounds__(256) void k0_splitW(const float* __restrict__ W1,
                                                 u16* __restrict__ wh, u16* __restrict__ wl)
{
    const int kc = blockIdx.x;      // 16 chunks of K=32
    const int h  = threadIdx.x;     // 256
    const int swz = (h >> 1) & 3;   // frag-row swizzle
    u16 rh[32], rl[32];
#pragma unroll
    for (int kk = 0; kk < 32; ++kk) {
        float a = W1[(size_t)(kc * 32 + kk) * HH + h];
        u16 hi = bf16rne(a);
        float lo = a - bf16tof(hi);
        rh[kk] = hi; rl[kk] = bf16rne(lo);
    }
    const size_t base = (size_t)kc * 8192 + (size_t)h * 32;
#pragma unroll
    for (int q = 0; q < 4; ++q) {
        uint4 ph, pl;
        ph.x = (u32)rh[q*8+0] | ((u32)rh[q*8+1] << 16);
        ph.y = (u32)rh[q*8+2] | ((u32)rh[q*8+3] << 16);
        ph.z = (u32)rh[q*8+4] | ((u32)rh[q*8+5] << 16);
        ph.w = (u32)rh[q*8+6] | ((u32)rh[q*8+7] << 16);
        pl.x = (u32)rl[q*8+0] | ((u32)rl[q*8+1] << 16);
        pl.y = (u32)rl[q*8+2] | ((u32)rl[q*8+3] << 16);
        pl.z = (u32)rl[q*8+4] | ((u32)rl[q*8+5] << 16);
        pl.w = (u32)rl[q*8+6] | ((u32)rl[q*8+7] << 16);
        const int qs = (q ^ swz) * 8;
        *(uint4*)&wh[base + qs] = ph;
        *(uint4*)&wl[base + qs] = pl;
    }
}

// -------- Kernel 1 v3: counted-vmcnt software pipeline ----
// Round-2 evidence: conflicts=0 yet 168us, MfmaUtil 26%, 54% stall -> the
// exposed per-kc HBM latency (geo loads) + __syncthreads vmcnt(0) drains are
// the bottleneck. This version uses raw s_barrier + counted s_waitcnt so the
// geo/obj register prefetch (issued one kc ahead) and nothing else stays in
// flight across barriers (T3/T4/T14 recipe).
// vmcnt bookkeeping per wave per iter: [8x global_load_lds B(kc) issued at end
// of iter kc-1] then [4x dwordx4 prefetch g/o(kc+1)]. Compiler waits vmcnt(8)
// for prefetch use; manual vmcnt(4) before barrier A retires the 8 DMAs.
__global__ __launch_bounds__(256, 2) void k1_pair_mfma(
    const float* __restrict__ obj, const float* __restrict__ geo,
    const u16* __restrict__ wh, const u16* __restrict__ wl,
    const float* __restrict__ b1, const float* __restrict__ w2,
    float* __restrict__ logits_acc)
{
    const int jb = blockIdx.x, i = blockIdx.y, r = blockIdx.z;
    const int j0 = jb * 64;
    const int tid = threadIdx.x;
    const int lane = tid & 63, wv = tid >> 6;
    const int l15 = lane & 15, quad = lane >> 4;
    const int fsl = (quad ^ ((l15 >> 1) & 3)) * 8;   // swizzled frag slot (u16)

    __shared__ float sObjI[DD];
    __shared__ __align__(16) u16 sAh[64 * 32], sAl[64 * 32];
    __shared__ __align__(16) u16 sBh[256 * 32], sBl[256 * 32];

    const float* objI = obj + (size_t)(r * NN + i) * DD;
    for (int t = tid; t < DD; t += 256) sObjI[t] = objI[t];

    f32x4 acc[4][4];
#pragma unroll
    for (int mt = 0; mt < 4; ++mt)
#pragma unroll
        for (int nt = 0; nt < 4; ++nt) acc[mt][nt] = (f32x4){0.f, 0.f, 0.f, 0.f};

    const float* geoB = geo + ((size_t)(r * NN + i) * NN + j0) * DD;
    const float* objJ = obj + (size_t)(r * NN + j0) * DD;

    const int aj = tid >> 2;            // j row this thread generates (0..63)
    const int ak = (tid & 3) * 8;       // k offset within chunk (0,8,16,24)
    const int asl = ((tid & 3) ^ ((aj >> 1) & 3)) * 8;  // swizzled A write slot

#define STAGE_B(KC) do { \
    const char* gh_ = (const char*)(wh + (size_t)(KC) * 8192); \
    const char* gl_ = (const char*)(wl + (size_t)(KC) * 8192); \
    _Pragma("unroll") \
    for (int p_ = 0; p_ < 4; ++p_) { \
        const int off_ = (wv * 4 + p_) * 1024; \
        __builtin_amdgcn_global_load_lds( \
            (const __attribute__((address_space(1))) u32*)(gh_ + off_ + lane * 16), \
            (__attribute__((address_space(3))) u32*)((char*)sBh + off_), 16, 0, 0); \
        __builtin_amdgcn_global_load_lds( \
            (const __attribute__((address_space(1))) u32*)(gl_ + off_ + lane * 16), \
            (__attribute__((address_space(3))) u32*)((char*)sBl + off_), 16, 0, 0); \
    } \
} while (0)

    // ---- prologue: B[0] DMA + geo/obj regs for kc=0 in flight ----
    STAGE_B(0);
    float4 g0 = *(const float4*)(geoB + (size_t)aj * DD + ak);
    float4 g1 = *(const float4*)(geoB + (size_t)aj * DD + ak + 4);
    float4 o0 = *(const float4*)(objJ + (size_t)aj * DD + ak);
    float4 o1 = *(const float4*)(objJ + (size_t)aj * DD + ak + 4);
    asm volatile("s_waitcnt lgkmcnt(0)" ::: "memory");   // sObjI writes drained
    __builtin_amdgcn_s_barrier();

#pragma unroll 1
    for (int kc = 0; kc < 16; ++kc) {
        const int k0 = kc * 32;
        // ---- PACK phase: consume prefetched g/o (compiler emits vmcnt wait) ----
        float a[8];
        a[0] = fmaf(sObjI[k0+ak+0], o0.x, g0.x);
        a[1] = fmaf(sObjI[k0+ak+1], o0.y, g0.y);
        a[2] = fmaf(sObjI[k0+ak+2], o0.z, g0.z);
        a[3] = fmaf(sObjI[k0+ak+3], o0.w, g0.w);
        a[4] = fmaf(sObjI[k0+ak+4], o1.x, g1.x);
        a[5] = fmaf(sObjI[k0+ak+5], o1.y, g1.y);
        a[6] = fmaf(sObjI[k0+ak+6], o1.z, g1.z);
        a[7] = fmaf(sObjI[k0+ak+7], o1.w, g1.w);
        // ---- issue prefetch for kc+1 (clamped: uniform vmcnt counts) ----
        {
            const int kp = (kc < 15) ? (kc + 1) * 32 : 15 * 32;
            const float* gp = geoB + (size_t)aj * DD + kp + ak;
            const float* op = objJ + (size_t)aj * DD + kp + ak;
            g0 = *(const float4*)gp;  g1 = *(const float4*)(gp + 4);
            o0 = *(const float4*)op;  o1 = *(const float4*)(op + 4);
        }
        // ---- split & write A tile ----
        {
            u16 hs[8], ls[8];
#pragma unroll
            for (int q = 0; q < 8; ++q) {
                hs[q] = bf16rne(a[q]);
                ls[q] = bf16rne(a[q] - bf16tof(hs[q]));
            }
            uint4 ph, pl;
            ph.x = (u32)hs[0] | ((u32)hs[1] << 16); ph.y = (u32)hs[2] | ((u32)hs[3] << 16);
            ph.z = (u32)hs[4] | ((u32)hs[5] << 16); ph.w = (u32)hs[6] | ((u32)hs[7] << 16);
            pl.x = (u32)ls[0] | ((u32)ls[1] << 16); pl.y = (u32)ls[2] | ((u32)ls[3] << 16);
            pl.z = (u32)ls[4] | ((u32)ls[5] << 16); pl.w = (u32)ls[6] | ((u32)ls[7] << 16);
            *(uint4*)&sAh[aj * 32 + asl] = ph;
            *(uint4*)&sAl[aj * 32 + asl] = pl;
        }
        // A writes drained + own 8 B-DMAs retired (4 youngest = prefetch stay in flight);
        // wait-THEN-barrier so every wave's stores are visible after the barrier.
        asm volatile("s_waitcnt vmcnt(4) lgkmcnt(0)" ::: "memory");
        __builtin_amdgcn_s_barrier();
        // ---- FRAG phase ----
        bf16x8 Bh[4], Bl[4], Ah[4], Al[4];
#pragma unroll
        for (int nt = 0; nt < 4; ++nt) {
            const int row = wv * 64 + nt * 16 + l15;
            Bh[nt] = *(const bf16x8*)&sBh[row * 32 + fsl];
            Bl[nt] = *(const bf16x8*)&sBl[row * 32 + fsl];
        }
#pragma unroll
        for (int mt = 0; mt < 4; ++mt) {
            const int row = mt * 16 + l15;
            Ah[mt] = *(const bf16x8*)&sAh[row * 32 + fsl];
            Al[mt] = *(const bf16x8*)&sAl[row * 32 + fsl];
        }
        // frag reads retired before barrier -> safe for next-iter LDS overwrites
        asm volatile("s_waitcnt lgkmcnt(0)" ::: "memory");
        __builtin_amdgcn_s_barrier();
        // ---- issue next B-DMA; its latency is covered by MFMA + next PACK ----
        if (kc < 15) STAGE_B(kc + 1);
        __builtin_amdgcn_s_setprio(1);
#pragma unroll
        for (int mt = 0; mt < 4; ++mt)
#pragma unroll
            for (int nt = 0; nt < 4; ++nt) {
                acc[mt][nt] = __builtin_amdgcn_mfma_f32_16x16x32_bf16(Ah[mt], Bh[nt], acc[mt][nt], 0, 0, 0);
                acc[mt][nt] = __builtin_amdgcn_mfma_f32_16x16x32_bf16(Ah[mt], Bl[nt], acc[mt][nt], 0, 0, 0);
                acc[mt][nt] = __builtin_amdgcn_mfma_f32_16x16x32_bf16(Al[mt], Bh[nt], acc[mt][nt], 0, 0, 0);
            }
        __builtin_amdgcn_s_setprio(0);
    }
#undef STAGE_B

    float pr[4][4];
#pragma unroll
    for (int mt = 0; mt < 4; ++mt)
#pragma unroll
        for (int t = 0; t < 4; ++t) pr[mt][t] = 0.f;
#pragma unroll
    for (int nt = 0; nt < 4; ++nt) {
        const int h = wv * 64 + nt * 16 + l15;
        const float bb = b1[h], w = w2[h];
#pragma unroll
        for (int mt = 0; mt < 4; ++mt)
#pragma unroll
            for (int t = 0; t < 4; ++t)
                pr[mt][t] += fmaxf(acc[mt][nt][t] + bb, 0.f) * w;
    }
#pragma unroll
    for (int mt = 0; mt < 4; ++mt)
#pragma unroll
        for (int t = 0; t < 4; ++t) {
            float v = pr[mt][t];
            v += __shfl_xor(v, 1); v += __shfl_xor(v, 2);
            v += __shfl_xor(v, 4); v += __shfl_xor(v, 8);
            if (l15 == 0)
                atomicAdd(&logits_acc[i * NN + j0 + mt * 16 + quad * 4 + t], v);
        }
}

// -------- Kernel 2: finalize o2o logits (out0) + radix-threshold candidate select ----
__global__ __launch_bounds__(1024) void k2_hist(
    const float* __restrict__ logits_acc, const float* __restrict__ mask,
    const float* __restrict__ b2a, float* __restrict__ out,
    int* __restrict__ cand, int* __restrict__ cnt_out)
{
    __shared__ u32 hist[16 * 256];   // 16 replicated copies (hot-bin atomic fix)
    __shared__ u32 sum1[256];
    __shared__ int sB1, sRem, sT16;
    __shared__ u32 sCnt;
    const int t = threadIdx.x;
    const int hb = (t >> 6) << 8;    // this wave's histogram copy base
    for (int b = t; b < 16 * 256; b += 1024) hist[b] = 0;
    if (t == 0) sCnt = 0;
    __syncthreads();
    const float bias = b2a[0];
    u32 skey[16];
#pragma unroll
    for (int e = 0; e < 16; ++e) {
        const int idx = e * 1024 + t;
        const float lg = logits_acc[idx] * 0.125f + bias;
        out[idx] = lg;                       // output 0
        u32 s = f32sort(lg);
        if (mask[idx] == 0.f) s = 0;         // excluded (prob forced to 0)
        skey[e] = s;
        atomicAdd(&hist[hb + (s >> 24)], 1u);
    }
    __syncthreads();
    if (t < 256) {
        u32 s = 0;
#pragma unroll
        for (int c = 0; c < 16; ++c) s += hist[c * 256 + t];
        sum1[t] = s;
    }
    __syncthreads();
    if (t == 0) {
        u32 cum = 0; int b = 255;
        for (; b > 0; --b) { u32 c = sum1[b]; if (cum + c >= (u32)NSEL) break; cum += c; }
        sB1 = b; sRem = NSEL - (int)cum;
    }
    __syncthreads();
    const int B1 = sB1;
    for (int b = t; b < 16 * 256; b += 1024) hist[b] = 0;
    __syncthreads();
#pragma unroll
    for (int e = 0; e < 16; ++e) {
        const u32 s = skey[e];
        if ((int)(s >> 24) == B1) atomicAdd(&hist[hb + ((s >> 16) & 0xFF)], 1u);
    }
    __syncthreads();
    if (t < 256) {
        u32 s = 0;
#pragma unroll
        for (int c = 0; c < 16; ++c) s += hist[c * 256 + t];
        sum1[t] = s;
    }
    __syncthreads();
    if (t == 0) {
        const int rem = sRem; u32 cum = 0; int b = 255;
        for (; b > 0; --b) { cum += sum1[b]; if ((int)cum >= rem) break; }
        sT16 = (B1 << 8) | b;
    }
    __syncthreads();
    const u32 T16 = (u32)sT16;
#pragma unroll
    for (int e = 0; e < 16; ++e) {
        const u32 s = skey[e];
        if (s != 0 && (s >> 16) >= T16) {
            const u32 pos = atomicAdd(&sCnt, 1u);
            if (pos < (u32)NCAND) cand[pos] = e * 1024 + t;
        }
    }
    __syncthreads();
    if (t == 0) *cnt_out = (int)(sCnt < (u32)NCAND ? sCnt : (u32)NCAND);
}

// -------- Kernel 5: exact fp32 recompute of candidate logits ----
__global__ __launch_bounds__(256) void k5_exact(
    const float* __restrict__ obj, const float* __restrict__ geo,
    const float* __restrict__ W1, const float* __restrict__ b1,
    const float* __restrict__ w2, const float* __restrict__ b2a,
    const int* __restrict__ cand, const int* __restrict__ cnt_ptr,
    float* __restrict__ exact)
{
    const int c = blockIdx.x;
    if (c >= *cnt_ptr) { if (threadIdx.x == 0) exact[c] = -1e30f; return; }
    const int idx = cand[c];
    const int i = idx >> 7, j = idx & 127;
    const int t = threadIdx.x;
    __shared__ float sA[RR][DD];
    __shared__ float sRed[4];
    for (int f = t; f < RR * DD; f += 256) {
        const int r = f >> 9, k = f & 511;
        sA[r][k] = fmaf(obj[(size_t)(r * NN + i) * DD + k],
                        obj[(size_t)(r * NN + j) * DD + k],
                        geo[((size_t)(r * NN + i) * NN + j) * DD + k]);
    }
    __syncthreads();
    float hv[RR];
#pragma unroll
    for (int r = 0; r < RR; ++r) hv[r] = 0.f;
#pragma unroll 4
    for (int k = 0; k < DD; ++k) {
        const float w = W1[(size_t)k * HH + t];
#pragma unroll
        for (int r = 0; r < RR; ++r) hv[r] = fmaf(sA[r][k], w, hv[r]);
    }
    const float bb = b1[t], wv2 = w2[t];
    float p = 0.f;
#pragma unroll
    for (int r = 0; r < RR; ++r) p += fmaxf(hv[r] + bb, 0.f) * wv2;
#pragma unroll
    for (int off = 1; off < 64; off <<= 1) p += __shfl_xor(p, off);
    if ((t & 63) == 0) sRed[t >> 6] = p;
    __syncthreads();
    if (t == 0) exact[c] = (sRed[0] + sRed[1] + sRed[2] + sRed[3]) * 0.125f + b2a[0];
}

// -------- Kernel 2b: bitonic re-rank of candidates by exact prob -> top-64 (out2) ----
__global__ __launch_bounds__(256) void k_sort(
    const float* __restrict__ exact, const int* __restrict__ cand,
    float* __restrict__ out, int* __restrict__ topk)
{
    __shared__ u64 sKey[NCAND];
    const int t = threadIdx.x;
    {
        const float lg = exact[t];
        u32 ps = 0; u32 idx = 0x7FFFFFFFu;
        if (lg > -1e29f) {
            const float p = 1.f / (1.f + expf(-lg));
            ps = f32sort(p);
            idx = (u32)cand[t];
        }
        sKey[t] = ((u64)ps << 32) | (u64)(0xFFFFFFFFu - idx);
    }
    for (int k = 2; k <= NCAND; k <<= 1)
        for (int j = k >> 1; j > 0; j >>= 1) {
            __syncthreads();
            const int ixj = t ^ j;
            if (ixj > t) {
                const u64 a = sKey[t], b = sKey[ixj];
                if (((t & k) == 0) ? (a < b) : (a > b)) { sKey[t] = b; sKey[ixj] = a; }
            }
        }
    __syncthreads();
    if (t < KTOP) {
        const u32 idx = 0xFFFFFFFFu - (u32)(sKey[t] & 0xFFFFFFFFull);
        topk[t] = (int)idx;
        out[20480 + t] = (float)idx;      // output 2
    }
}

// -------- Kernel 3: gather averaged pair features for final top-64 ----
__global__ __launch_bounds__(256) void k3_gather(
    const float* __restrict__ obj, const float* __restrict__ geo,
    const int* __restrict__ ws_topk, float* __restrict__ pf)
{
    const int tix = blockIdx.x;            // 0..63
    const int idx = ws_topk[tix];
    const int i = idx >> 7, j = idx & 127;
    for (int dd = threadIdx.x; dd < DD; dd += 256) {
        float s = 0.f;
#pragma unroll
        for (int r = 0; r < RR; ++r) {
            const float oi = obj[(size_t)(r * NN + i) * DD + dd];
            const float oj = obj[(size_t)(r * NN + j) * DD + dd];
            const float g  = geo[((size_t)(r * NN + i) * NN + j) * DD + dd];
            s += oi * oj + g;
        }
        pf[tix * DD + dd] = s * 0.125f;
    }
}

// -------- Kernel 4: fused p2p MLP, one block per row a, full K, direct write ----
__global__ __launch_bounds__(256) void k4_p2p(
    const float* __restrict__ pf, const float* __restrict__ W1,
    const float* __restrict__ b1, const float* __restrict__ w2,
    const float* __restrict__ b2, float* __restrict__ out)
{
    const int a = blockIdx.x;
    const int tid = threadIdx.x;
    const int tx = tid & 15, ty = tid >> 4;

    __shared__ float sPfA[DD];
    __shared__ __align__(16) float sA[32][68];
    __shared__ __align__(16) float sB[32][HH];

    const float* pfA = pf + (size_t)a * DD;
    for (int t = tid; t < DD; t += 256) sPfA[t] = pfA[t];

    float acc[4][16];
#pragma unroll
    for (int m = 0; m < 4; ++m)
#pragma unroll
        for (int n = 0; n < 16; ++n) acc[m][n] = 0.f;

    for (int kc = 0; kc < 16; ++kc) {
        const int k0 = kc * 32;
        __syncthreads();
#pragma unroll
        for (int p = 0; p < 8; ++p) {
            const int f = tid + p * 256;
            const int kk = f >> 6, c = (f & 63) << 2;
            *(float4*)&sB[kk][c] = *(const float4*)&W1[(size_t)(k0 + kk) * HH + c];
        }
#pragma unroll
        for (int p = 0; p < 2; ++p) {
            const int f = tid + p * 256;
            const int j = f >> 3, kk = (f & 7) << 2;
            float4 o = *(const float4*)(pf + (size_t)j * DD + k0 + kk);
            sA[kk + 0][j] = sPfA[k0 + kk + 0] * o.x;
            sA[kk + 1][j] = sPfA[k0 + kk + 1] * o.y;
            sA[kk + 2][j] = sPfA[k0 + kk + 2] * o.z;
            sA[kk + 3][j] = sPfA[k0 + kk + 3] * o.w;
        }
        __syncthreads();
#pragma unroll 8
        for (int kk = 0; kk < 32; ++kk) {
            float4 a4 = *(const float4*)&sA[kk][ty << 2];
            float av[4] = {a4.x, a4.y, a4.z, a4.w};
#pragma unroll
            for (int n4 = 0; n4 < 4; ++n4) {
                float4 b4 = *(const float4*)&sB[kk][(n4 << 6) + (tx << 2)];
                float bv[4] = {b4.x, b4.y, b4.z, b4.w};
#pragma unroll
                for (int m = 0; m < 4; ++m)
#pragma unroll
                    for (int c = 0; c < 4; ++c)
                        acc[m][(n4 << 2) + c] = fmaf(av[m], bv[c], acc[m][(n4 << 2) + c]);
            }
        }
    }
    const float b20 = b2[0];
    float pr[4] = {0.f, 0.f, 0.f, 0.f};
#pragma unroll
    for (int n4 = 0; n4 < 4; ++n4)
#pragma unroll
        for (int c = 0; c < 4; ++c) {
            const int h = (n4 << 6) + (tx << 2) + c;
            const float bb = b1[h], w = w2[h];
#pragma unroll
            for (int m = 0; m < 4; ++m)
                pr[m] += fmaxf(acc[m][(n4 << 2) + c] + bb, 0.f) * w;
        }
#pragma unroll
    for (int m = 0; m < 4; ++m) {
        pr[m] += __shfl_xor(pr[m], 1); pr[m] += __shfl_xor(pr[m], 2);
        pr[m] += __shfl_xor(pr[m], 4); pr[m] += __shfl_xor(pr[m], 8);
        if (tx == 0)
            out[16384 + a * 64 + (ty << 2) + m] = pr[m] + b20;  // output 1
    }
}

extern "C" void kernel_launch(void* const* d_in, const int* in_sizes, int n_in,
                              void* d_out, int out_size, void* d_ws, size_t ws_size,
                              hipStream_t stream) {
    const float* obj  = (const float*)d_in[0];
    const float* geo  = (const float*)d_in[1];
    const float* mask = (const float*)d_in[2];
    const float* w1a  = (const float*)d_in[3];
    const float* b1a  = (const float*)d_in[4];
    const float* w2a  = (const float*)d_in[5];
    const float* b2a  = (const float*)d_in[6];
    const float* w1b  = (const float*)d_in[7];
    const float* b1b  = (const float*)d_in[8];
    const float* w2b  = (const float*)d_in[9];
    const float* b2b  = (const float*)d_in[10];
    float* out = (float*)d_out;

    char* ws = (char*)d_ws;
    float* ws_logits = (float*)(ws + WS_LOGITS_OFF);
    int*   ws_cand   = (int*)  (ws + WS_CAND_OFF);
    float* ws_exact  = (float*)(ws + WS_EXACT_OFF);
    int*   ws_cnt    = (int*)  (ws + WS_CNT_OFF);
    int*   ws_topk   = (int*)  (ws + WS_TOPK_OFF);
    float* ws_pf     = (float*)(ws + WS_PF_OFF);
    u16*   ws_wh     = (u16*)  (ws + WS_WH_OFF);
    u16*   ws_wl     = (u16*)  (ws + WS_WL_OFF);

    hipMemsetAsync(ws_logits, 0, 16384 * sizeof(float), stream);

    k0_splitW<<<16, 256, 0, stream>>>(w1a, ws_wh, ws_wl);
    k1_pair_mfma<<<dim3(2, NN, RR), 256, 0, stream>>>(obj, geo, ws_wh, ws_wl, b1a, w2a, ws_logits);
    k2_hist<<<1, 1024, 0, stream>>>(ws_logits, mask, b2a, out, ws_cand, ws_cnt);
    k5_exact<<<NCAND, 256, 0, stream>>>(obj, geo, w1a, b1a, w2a, b2a, ws_cand, ws_cnt, ws_exact);
    k_sort<<<1, 256, 0, stream>>>(ws_exact, ws_cand, out, ws_topk);
    k3_gather<<<KTOP, 256, 0, stream>>>(obj, geo, ws_topk, ws_pf);
    k4_p2p<<<KTOP, 256, 0, stream>>>(ws_pf, w1b, b1b, w2b, b2b, out);
}

// Round 4
// 546.029 us; speedup vs baseline: 2.4431x; 1.1637x over previous
//
#include <hip/hip_runtime.h>
#include <math.h>

typedef unsigned int u32;
typedef unsigned long long u64;
typedef unsigned short u16;
typedef short bf16x8 __attribute__((ext_vector_type(8)));
typedef float f32x4 __attribute__((ext_vector_type(4)));

#define RR 8
#define NN 128
#define DD 512
#define HH 256
#define KTOP 64
#define NCAND 256    // candidate buffer size
#define NSEL 128     // min candidates selected by threshold

// ws layout (bytes)
#define WS_LOGITS_OFF 0         // 16384 f32
#define WS_CAND_OFF   65536     // 256 i32
#define WS_EXACT_OFF  66560     // 256 f32
#define WS_CNT_OFF    67584     // 1 i32 (+pad)
#define WS_TOPK_OFF   67600     // 64 i32 (unused now, kept for layout stability)
#define WS_PF_OFF     67856     // 64*512 f32
#define WS_WH_OFF     198928    // 512*256 u16 (bf16-hi of W1a, chunk-transposed+swizzled)
#define WS_WL_OFF     461072    // 512*256 u16 (bf16-lo)

__device__ __forceinline__ u16 bf16rne(float x) {
    union { float f; u32 u; } v; v.f = x;
    u32 r = (v.u + 0x7fffu + ((v.u >> 16) & 1u)) >> 16;
    return (u16)r;
}
__device__ __forceinline__ float bf16tof(u16 h) {
    union { float f; u32 u; } v; v.u = ((u32)h) << 16; return v.f;
}
__device__ __forceinline__ u32 f32sort(float x) {
    union { float f; u32 u; } v; v.f = x;
    return v.u ^ ((v.u & 0x80000000u) ? 0xFFFFFFFFu : 0x80000000u);
}

// -------- Kernel 0: split W1a into bf16 hi/lo, layout [kc][h][slot^swz], swz=(h>>1)&3 ----
// Block 16 zeroes the logits accumulator (replaces the separate hipMemsetAsync).
// XOR swizzle baked into the GLOBAL layout so linear global_load_lds staging in
// k1 lands a bank-conflict-free LDS image. HW-verified: SQ_LDS_BANK_CONFLICT == 0.
__global__ __launch_bounds__(256) void k0_splitW(const float* __restrict__ W1,
                                                 u16* __restrict__ wh, u16* __restrict__ wl,
                                                 float* __restrict__ logits)
{
    if (blockIdx.x == 16) {
        float4 z = {0.f, 0.f, 0.f, 0.f};
        for (int t = threadIdx.x; t < 4096; t += 256)
            ((float4*)logits)[t] = z;
        return;
    }
    const int kc = blockIdx.x;      // 16 chunks of K=32
    const int h  = threadIdx.x;     // 256
    const int swz = (h >> 1) & 3;   // frag-row swizzle
    u16 rh[32], rl[32];
#pragma unroll
    for (int kk = 0; kk < 32; ++kk) {
        float a = W1[(size_t)(kc * 32 + kk) * HH + h];
        u16 hi = bf16rne(a);
        float lo = a - bf16tof(hi);
        rh[kk] = hi; rl[kk] = bf16rne(lo);
    }
    const size_t base = (size_t)kc * 8192 + (size_t)h * 32;
#pragma unroll
    for (int q = 0; q < 4; ++q) {
        uint4 ph, pl;
        ph.x = (u32)rh[q*8+0] | ((u32)rh[q*8+1] << 16);
        ph.y = (u32)rh[q*8+2] | ((u32)rh[q*8+3] << 16);
        ph.z = (u32)rh[q*8+4] | ((u32)rh[q*8+5] << 16);
        ph.w = (u32)rh[q*8+6] | ((u32)rh[q*8+7] << 16);
        pl.x = (u32)rl[q*8+0] | ((u32)rl[q*8+1] << 16);
        pl.y = (u32)rl[q*8+2] | ((u32)rl[q*8+3] << 16);
        pl.z = (u32)rl[q*8+4] | ((u32)rl[q*8+5] << 16);
        pl.w = (u32)rl[q*8+6] | ((u32)rl[q*8+7] << 16);
        const int qs = (q ^ swz) * 8;
        *(uint4*)&wh[base + qs] = ph;
        *(uint4*)&wl[base + qs] = pl;
    }
}

// -------- Kernel 1: first-MLP logits via split-bf16 MFMA (round-2 best: ~168us) ----
// Round-1 lesson: don't force waves/EU (spills). Round-3 lesson: counted-vmcnt
// pipelining on this 2-barrier structure is neutral. Keep the simple form.
__global__ __launch_bounds__(256, 2) void k1_pair_mfma(
    const float* __restrict__ obj, const float* __restrict__ geo,
    const u16* __restrict__ wh, const u16* __restrict__ wl,
    const float* __restrict__ b1, const float* __restrict__ w2,
    float* __restrict__ logits_acc)
{
    const int jb = blockIdx.x, i = blockIdx.y, r = blockIdx.z;
    const int j0 = jb * 64;
    const int tid = threadIdx.x;
    const int lane = tid & 63, wv = tid >> 6;
    const int l15 = lane & 15, quad = lane >> 4;
    const int fsl = (quad ^ ((l15 >> 1) & 3)) * 8;   // swizzled frag slot (u16)

    __shared__ float sObjI[DD];
    __shared__ __align__(16) u16 sAh[64 * 32], sAl[64 * 32];
    __shared__ __align__(16) u16 sBh[256 * 32], sBl[256 * 32];

    const float* objI = obj + (size_t)(r * NN + i) * DD;
    for (int t = tid; t < DD; t += 256) sObjI[t] = objI[t];

    f32x4 acc[4][4];
#pragma unroll
    for (int mt = 0; mt < 4; ++mt)
#pragma unroll
        for (int nt = 0; nt < 4; ++nt) acc[mt][nt] = (f32x4){0.f, 0.f, 0.f, 0.f};

    const float* geoB = geo + ((size_t)(r * NN + i) * NN + j0) * DD;
    const float* objJ = obj + (size_t)(r * NN + j0) * DD;

    const int aj = tid >> 2;            // j row this thread generates (0..63)
    const int ak = (tid & 3) * 8;       // k offset within chunk (0,8,16,24)
    const int asl = ((tid & 3) ^ ((aj >> 1) & 3)) * 8;  // swizzled A write slot

    for (int kc = 0; kc < 16; ++kc) {
        const int k0 = kc * 32;
        __syncthreads();
        {
            const char* gh = (const char*)(wh + (size_t)kc * 8192);
            const char* gl = (const char*)(wl + (size_t)kc * 8192);
#pragma unroll
            for (int p = 0; p < 4; ++p) {
                const int off = (wv * 4 + p) * 1024;   // bytes; wave-uniform
                __builtin_amdgcn_global_load_lds(
                    (const __attribute__((address_space(1))) u32*)(gh + off + lane * 16),
                    (__attribute__((address_space(3))) u32*)((char*)sBh + off), 16, 0, 0);
                __builtin_amdgcn_global_load_lds(
                    (const __attribute__((address_space(1))) u32*)(gl + off + lane * 16),
                    (__attribute__((address_space(3))) u32*)((char*)sBl + off), 16, 0, 0);
            }
        }
        {
            float4 g0 = *(const float4*)(geoB + (size_t)aj * DD + k0 + ak);
            float4 g1 = *(const float4*)(geoB + (size_t)aj * DD + k0 + ak + 4);
            float4 o0 = *(const float4*)(objJ + (size_t)aj * DD + k0 + ak);
            float4 o1 = *(const float4*)(objJ + (size_t)aj * DD + k0 + ak + 4);
            float a[8];
            a[0] = fmaf(sObjI[k0+ak+0], o0.x, g0.x);
            a[1] = fmaf(sObjI[k0+ak+1], o0.y, g0.y);
            a[2] = fmaf(sObjI[k0+ak+2], o0.z, g0.z);
            a[3] = fmaf(sObjI[k0+ak+3], o0.w, g0.w);
            a[4] = fmaf(sObjI[k0+ak+4], o1.x, g1.x);
            a[5] = fmaf(sObjI[k0+ak+5], o1.y, g1.y);
            a[6] = fmaf(sObjI[k0+ak+6], o1.z, g1.z);
            a[7] = fmaf(sObjI[k0+ak+7], o1.w, g1.w);
            u16 hs[8], ls[8];
#pragma unroll
            for (int q = 0; q < 8; ++q) {
                hs[q] = bf16rne(a[q]);
                ls[q] = bf16rne(a[q] - bf16tof(hs[q]));
            }
            uint4 ph, pl;
            ph.x = (u32)hs[0] | ((u32)hs[1] << 16); ph.y = (u32)hs[2] | ((u32)hs[3] << 16);
            ph.z = (u32)hs[4] | ((u32)hs[5] << 16); ph.w = (u32)hs[6] | ((u32)hs[7] << 16);
            pl.x = (u32)ls[0] | ((u32)ls[1] << 16); pl.y = (u32)ls[2] | ((u32)ls[3] << 16);
            pl.z = (u32)ls[4] | ((u32)ls[5] << 16); pl.w = (u32)ls[6] | ((u32)ls[7] << 16);
            *(uint4*)&sAh[aj * 32 + asl] = ph;
            *(uint4*)&sAl[aj * 32 + asl] = pl;
        }
        __syncthreads();
        bf16x8 Bh[4], Bl[4], Ah[4], Al[4];
#pragma unroll
        for (int nt = 0; nt < 4; ++nt) {
            const int row = wv * 64 + nt * 16 + l15;
            Bh[nt] = *(const bf16x8*)&sBh[row * 32 + fsl];
            Bl[nt] = *(const bf16x8*)&sBl[row * 32 + fsl];
        }
#pragma unroll
        for (int mt = 0; mt < 4; ++mt) {
            const int row = mt * 16 + l15;
            Ah[mt] = *(const bf16x8*)&sAh[row * 32 + fsl];
            Al[mt] = *(const bf16x8*)&sAl[row * 32 + fsl];
        }
#pragma unroll
        for (int mt = 0; mt < 4; ++mt)
#pragma unroll
            for (int nt = 0; nt < 4; ++nt) {
                acc[mt][nt] = __builtin_amdgcn_mfma_f32_16x16x32_bf16(Ah[mt], Bh[nt], acc[mt][nt], 0, 0, 0);
                acc[mt][nt] = __builtin_amdgcn_mfma_f32_16x16x32_bf16(Ah[mt], Bl[nt], acc[mt][nt], 0, 0, 0);
                acc[mt][nt] = __builtin_amdgcn_mfma_f32_16x16x32_bf16(Al[mt], Bh[nt], acc[mt][nt], 0, 0, 0);
            }
    }
    float pr[4][4];
#pragma unroll
    for (int mt = 0; mt < 4; ++mt)
#pragma unroll
        for (int t = 0; t < 4; ++t) pr[mt][t] = 0.f;
#pragma unroll
    for (int nt = 0; nt < 4; ++nt) {
        const int h = wv * 64 + nt * 16 + l15;
        const float bb = b1[h], w = w2[h];
#pragma unroll
        for (int mt = 0; mt < 4; ++mt)
#pragma unroll
            for (int t = 0; t < 4; ++t)
                pr[mt][t] += fmaxf(acc[mt][nt][t] + bb, 0.f) * w;
    }
#pragma unroll
    for (int mt = 0; mt < 4; ++mt)
#pragma unroll
        for (int t = 0; t < 4; ++t) {
            float v = pr[mt][t];
            v += __shfl_xor(v, 1); v += __shfl_xor(v, 2);
            v += __shfl_xor(v, 4); v += __shfl_xor(v, 8);
            if (l15 == 0)
                atomicAdd(&logits_acc[i * NN + j0 + mt * 16 + quad * 4 + t], v);
        }
}

// -------- Kernel 2: finalize o2o logits (out0) + radix-threshold candidate select ----
__global__ __launch_bounds__(1024) void k2_hist(
    const float* __restrict__ logits_acc, const float* __restrict__ mask,
    const float* __restrict__ b2a, float* __restrict__ out,
    int* __restrict__ cand, int* __restrict__ cnt_out)
{
    __shared__ u32 hist[16 * 256];   // 16 replicated copies (hot-bin atomic fix)
    __shared__ u32 sum1[256];
    __shared__ int sB1, sRem, sT16;
    __shared__ u32 sCnt;
    const int t = threadIdx.x;
    const int hb = (t >> 6) << 8;    // this wave's histogram copy base
    for (int b = t; b < 16 * 256; b += 1024) hist[b] = 0;
    if (t == 0) sCnt = 0;
    __syncthreads();
    const float bias = b2a[0];
    u32 skey[16];
#pragma unroll
    for (int e = 0; e < 16; ++e) {
        const int idx = e * 1024 + t;
        const float lg = logits_acc[idx] * 0.125f + bias;
        out[idx] = lg;                       // output 0
        u32 s = f32sort(lg);
        if (mask[idx] == 0.f) s = 0;         // excluded (prob forced to 0)
        skey[e] = s;
        atomicAdd(&hist[hb + (s >> 24)], 1u);
    }
    __syncthreads();
    if (t < 256) {
        u32 s = 0;
#pragma unroll
        for (int c = 0; c < 16; ++c) s += hist[c * 256 + t];
        sum1[t] = s;
    }
    __syncthreads();
    if (t == 0) {
        u32 cum = 0; int b = 255;
        for (; b > 0; --b) { u32 c = sum1[b]; if (cum + c >= (u32)NSEL) break; cum += c; }
        sB1 = b; sRem = NSEL - (int)cum;
    }
    __syncthreads();
    const int B1 = sB1;
    for (int b = t; b < 16 * 256; b += 1024) hist[b] = 0;
    __syncthreads();
#pragma unroll
    for (int e = 0; e < 16; ++e) {
        const u32 s = skey[e];
        if ((int)(s >> 24) == B1) atomicAdd(&hist[hb + ((s >> 16) & 0xFF)], 1u);
    }
    __syncthreads();
    if (t < 256) {
        u32 s = 0;
#pragma unroll
        for (int c = 0; c < 16; ++c) s += hist[c * 256 + t];
        sum1[t] = s;
    }
    __syncthreads();
    if (t == 0) {
        const int rem = sRem; u32 cum = 0; int b = 255;
        for (; b > 0; --b) { cum += sum1[b]; if ((int)cum >= rem) break; }
        sT16 = (B1 << 8) | b;
    }
    __syncthreads();
    const u32 T16 = (u32)sT16;
#pragma unroll
    for (int e = 0; e < 16; ++e) {
        const u32 s = skey[e];
        if (s != 0 && (s >> 16) >= T16) {
            const u32 pos = atomicAdd(&sCnt, 1u);
            if (pos < (u32)NCAND) cand[pos] = e * 1024 + t;
        }
    }
    __syncthreads();
    if (t == 0) *cnt_out = (int)(sCnt < (u32)NCAND ? sCnt : (u32)NCAND);
}

// -------- Kernel 5: exact fp32 recompute of candidate logits ----
__global__ __launch_bounds__(256) void k5_exact(
    const float* __restrict__ obj, const float* __restrict__ geo,
    const float* __restrict__ W1, const float* __restrict__ b1,
    const float* __restrict__ w2, const float* __restrict__ b2a,
    const int* __restrict__ cand, const int* __restrict__ cnt_ptr,
    float* __restrict__ exact)
{
    const int c = blockIdx.x;
    if (c >= *cnt_ptr) { if (threadIdx.x == 0) exact[c] = -1e30f; return; }
    const int idx = cand[c];
    const int i = idx >> 7, j = idx & 127;
    const int t = threadIdx.x;
    __shared__ float sA[RR][DD];
    __shared__ float sRed[4];
    for (int f = t; f < RR * DD; f += 256) {
        const int r = f >> 9, k = f & 511;
        sA[r][k] = fmaf(obj[(size_t)(r * NN + i) * DD + k],
                        obj[(size_t)(r * NN + j) * DD + k],
                        geo[((size_t)(r * NN + i) * NN + j) * DD + k]);
    }
    __syncthreads();
    float hv[RR];
#pragma unroll
    for (int r = 0; r < RR; ++r) hv[r] = 0.f;
#pragma unroll 8
    for (int k = 0; k < DD; ++k) {
        const float w = W1[(size_t)k * HH + t];
#pragma unroll
        for (int r = 0; r < RR; ++r) hv[r] = fmaf(sA[r][k], w, hv[r]);
    }
    const float bb = b1[t], wv2 = w2[t];
    float p = 0.f;
#pragma unroll
    for (int r = 0; r < RR; ++r) p += fmaxf(hv[r] + bb, 0.f) * wv2;
#pragma unroll
    for (int off = 1; off < 64; off <<= 1) p += __shfl_xor(p, off);
    if ((t & 63) == 0) sRed[t >> 6] = p;
    __syncthreads();
    if (t == 0) exact[c] = (sRed[0] + sRed[1] + sRed[2] + sRed[3]) * 0.125f + b2a[0];
}

// -------- Kernel SG: fused bitonic re-rank + top-64 gather ----
// Each of the 64 blocks redundantly sorts the 256 candidates in LDS
// (deterministic: identical input + tie-break by index => identical result
// in every block), then block tix gathers pair features for rank tix.
// Block 0 additionally writes output 2. Replaces k_sort + k3_gather.
__global__ __launch_bounds__(256) void k_sortgather(
    const float* __restrict__ exact, const int* __restrict__ cand,
    const float* __restrict__ obj, const float* __restrict__ geo,
    float* __restrict__ out, float* __restrict__ pf)
{
    __shared__ u64 sKey[NCAND];
    const int t = threadIdx.x;
    {
        const float lg = exact[t];
        u32 ps = 0; u32 idx = 0x7FFFFFFFu;
        if (lg > -1e29f) {
            const float p = 1.f / (1.f + expf(-lg));
            ps = f32sort(p);
            idx = (u32)cand[t];
        }
        sKey[t] = ((u64)ps << 32) | (u64)(0xFFFFFFFFu - idx);
    }
    for (int k = 2; k <= NCAND; k <<= 1)
        for (int j = k >> 1; j > 0; j >>= 1) {
            __syncthreads();
            const int ixj = t ^ j;
            if (ixj > t) {
                const u64 a = sKey[t], b = sKey[ixj];
                if (((t & k) == 0) ? (a < b) : (a > b)) { sKey[t] = b; sKey[ixj] = a; }
            }
        }
    __syncthreads();
    const int tix = blockIdx.x;            // 0..63 (rank this block gathers)
    if (tix == 0 && t < KTOP) {
        const u32 oidx = 0xFFFFFFFFu - (u32)(sKey[t] & 0xFFFFFFFFull);
        out[20480 + t] = (float)oidx;      // output 2
    }
    const int idx = (int)(0xFFFFFFFFu - (u32)(sKey[tix] & 0xFFFFFFFFull));
    const int i = idx >> 7, j = idx & 127;
    for (int dd = t; dd < DD; dd += 256) {
        float s = 0.f;
#pragma unroll
        for (int r = 0; r < RR; ++r) {
            const float oi = obj[(size_t)(r * NN + i) * DD + dd];
            const float oj = obj[(size_t)(r * NN + j) * DD + dd];
            const float g  = geo[((size_t)(r * NN + i) * NN + j) * DD + dd];
            s += oi * oj + g;
        }
        pf[tix * DD + dd] = s * 0.125f;
    }
}

// -------- Kernel 4 v2: p2p MLP via split-bf16 MFMA ----
// Old k4 was LDS-BW-bound (~80 B LDS read per 64 fp32 MACs/thread). MFMA
// fragments cut LDS traffic ~80x. W1b split per-kc in-kernel (no extra ws).
// 4 split terms (AhBh+AhBl+AlBh+AlBl) keep out1 error below out0's.
__global__ __launch_bounds__(256) void k4_p2p(
    const float* __restrict__ pf, const float* __restrict__ W1,
    const float* __restrict__ b1, const float* __restrict__ w2,
    const float* __restrict__ b2, float* __restrict__ out)
{
    const int a = blockIdx.x;              // 0..63
    const int tid = threadIdx.x;
    const int lane = tid & 63, wv = tid >> 6;
    const int l15 = lane & 15, quad = lane >> 4;
    const int fsl = (quad ^ ((l15 >> 1) & 3)) * 8;

    __shared__ float sPfA[DD];
    __shared__ __align__(16) u16 sAh[64 * 32], sAl[64 * 32];
    __shared__ __align__(16) u16 sBh[256 * 32], sBl[256 * 32];
    __shared__ float sRed[4][64];

    const float* pfA = pf + (size_t)a * DD;
    for (int t = tid; t < DD; t += 256) sPfA[t] = pfA[t];

    f32x4 acc[4][4];
#pragma unroll
    for (int mt = 0; mt < 4; ++mt)
#pragma unroll
        for (int nt = 0; nt < 4; ++nt) acc[mt][nt] = (f32x4){0.f, 0.f, 0.f, 0.f};

    const int aj = tid >> 2;               // j row (0..63)
    const int ak = (tid & 3) * 8;
    const int asl = ((tid & 3) ^ ((aj >> 1) & 3)) * 8;
    const int swzB = (tid >> 1) & 3;       // B swizzle for column h=tid

    for (int kc = 0; kc < 16; ++kc) {
        const int k0 = kc * 32;
        __syncthreads();
        // ---- B tile: load W1b[k0+kk][tid], split, LDS (k0-equivalent layout) ----
        {
            u16 rh[32], rl[32];
#pragma unroll
            for (int kk = 0; kk < 32; ++kk) {
                float w = W1[(size_t)(k0 + kk) * HH + tid];
                u16 hi = bf16rne(w);
                rh[kk] = hi; rl[kk] = bf16rne(w - bf16tof(hi));
            }
#pragma unroll
            for (int q = 0; q < 4; ++q) {
                uint4 ph, pl;
                ph.x = (u32)rh[q*8+0] | ((u32)rh[q*8+1] << 16);
                ph.y = (u32)rh[q*8+2] | ((u32)rh[q*8+3] << 16);
                ph.z = (u32)rh[q*8+4] | ((u32)rh[q*8+5] << 16);
                ph.w = (u32)rh[q*8+6] | ((u32)rh[q*8+7] << 16);
                pl.x = (u32)rl[q*8+0] | ((u32)rl[q*8+1] << 16);
                pl.y = (u32)rl[q*8+2] | ((u32)rl[q*8+3] << 16);
                pl.z = (u32)rl[q*8+4] | ((u32)rl[q*8+5] << 16);
                pl.w = (u32)rl[q*8+6] | ((u32)rl[q*8+7] << 16);
                const int qs = (q ^ swzB) * 8;
                *(uint4*)&sBh[tid * 32 + qs] = ph;
                *(uint4*)&sBl[tid * 32 + qs] = pl;
            }
        }
        // ---- A tile: pf[a][k] * pf[j][k] ----
        {
            float4 p0 = *(const float4*)(pf + (size_t)aj * DD + k0 + ak);
            float4 p1 = *(const float4*)(pf + (size_t)aj * DD + k0 + ak + 4);
            float av[8];
            av[0] = sPfA[k0+ak+0] * p0.x; av[1] = sPfA[k0+ak+1] * p0.y;
            av[2] = sPfA[k0+ak+2] * p0.z; av[3] = sPfA[k0+ak+3] * p0.w;
            av[4] = sPfA[k0+ak+4] * p1.x; av[5] = sPfA[k0+ak+5] * p1.y;
            av[6] = sPfA[k0+ak+6] * p1.z; av[7] = sPfA[k0+ak+7] * p1.w;
            u16 hs[8], ls[8];
#pragma unroll
            for (int q = 0; q < 8; ++q) {
                hs[q] = bf16rne(av[q]);
                ls[q] = bf16rne(av[q] - bf16tof(hs[q]));
            }
            uint4 ph, pl;
            ph.x = (u32)hs[0] | ((u32)hs[1] << 16); ph.y = (u32)hs[2] | ((u32)hs[3] << 16);
            ph.z = (u32)hs[4] | ((u32)hs[5] << 16); ph.w = (u32)hs[6] | ((u32)hs[7] << 16);
            pl.x = (u32)ls[0] | ((u32)ls[1] << 16); pl.y = (u32)ls[2] | ((u32)ls[3] << 16);
            pl.z = (u32)ls[4] | ((u32)ls[5] << 16); pl.w = (u32)ls[6] | ((u32)ls[7] << 16);
            *(uint4*)&sAh[aj * 32 + asl] = ph;
            *(uint4*)&sAl[aj * 32 + asl] = pl;
        }
        __syncthreads();
        bf16x8 Bh[4], Bl[4], Ah[4], Al[4];
#pragma unroll
        for (int nt = 0; nt < 4; ++nt) {
            const int row = wv * 64 + nt * 16 + l15;
            Bh[nt] = *(const bf16x8*)&sBh[row * 32 + fsl];
            Bl[nt] = *(const bf16x8*)&sBl[row * 32 + fsl];
        }
#pragma unroll
        for (int mt = 0; mt < 4; ++mt) {
            const int row = mt * 16 + l15;
            Ah[mt] = *(const bf16x8*)&sAh[row * 32 + fsl];
            Al[mt] = *(const bf16x8*)&sAl[row * 32 + fsl];
        }
#pragma unroll
        for (int mt = 0; mt < 4; ++mt)
#pragma unroll
            for (int nt = 0; nt < 4; ++nt) {
                acc[mt][nt] = __builtin_amdgcn_mfma_f32_16x16x32_bf16(Ah[mt], Bh[nt], acc[mt][nt], 0, 0, 0);
                acc[mt][nt] = __builtin_amdgcn_mfma_f32_16x16x32_bf16(Ah[mt], Bl[nt], acc[mt][nt], 0, 0, 0);
                acc[mt][nt] = __builtin_amdgcn_mfma_f32_16x16x32_bf16(Al[mt], Bh[nt], acc[mt][nt], 0, 0, 0);
                acc[mt][nt] = __builtin_amdgcn_mfma_f32_16x16x32_bf16(Al[mt], Bl[nt], acc[mt][nt], 0, 0, 0);
            }
    }
    float pr[4][4];
#pragma unroll
    for (int mt = 0; mt < 4; ++mt)
#pragma unroll
        for (int t = 0; t < 4; ++t) pr[mt][t] = 0.f;
#pragma unroll
    for (int nt = 0; nt < 4; ++nt) {
        const int h = wv * 64 + nt * 16 + l15;
        const float bb = b1[h], w = w2[h];
#pragma unroll
        for (int mt = 0; mt < 4; ++mt)
#pragma unroll
            for (int t = 0; t < 4; ++t)
                pr[mt][t] += fmaxf(acc[mt][nt][t] + bb, 0.f) * w;
    }
#pragma unroll
    for (int mt = 0; mt < 4; ++mt)
#pragma unroll
        for (int t = 0; t < 4; ++t) {
            float v = pr[mt][t];
            v += __shfl_xor(v, 1); v += __shfl_xor(v, 2);
            v += __shfl_xor(v, 4); v += __shfl_xor(v, 8);
            if (l15 == 0)
                sRed[wv][mt * 16 + quad * 4 + t] = v;
        }
    __syncthreads();
    if (tid < 64)
        out[16384 + a * 64 + tid] =
            sRed[0][tid] + sRed[1][tid] + sRed[2][tid] + sRed[3][tid] + b2[0];
}

extern "C" void kernel_launch(void* const* d_in, const int* in_sizes, int n_in,
                              void* d_out, int out_size, void* d_ws, size_t ws_size,
                              hipStream_t stream) {
    const float* obj  = (const float*)d_in[0];
    const float* geo  = (const float*)d_in[1];
    const float* mask = (const float*)d_in[2];
    const float* w1a  = (const float*)d_in[3];
    const float* b1a  = (const float*)d_in[4];
    const float* w2a  = (const float*)d_in[5];
    const float* b2a  = (const float*)d_in[6];
    const float* w1b  = (const float*)d_in[7];
    const float* b1b  = (const float*)d_in[8];
    const float* w2b  = (const float*)d_in[9];
    const float* b2b  = (const float*)d_in[10];
    float* out = (float*)d_out;

    char* ws = (char*)d_ws;
    float* ws_logits = (float*)(ws + WS_LOGITS_OFF);
    int*   ws_cand   = (int*)  (ws + WS_CAND_OFF);
    float* ws_exact  = (float*)(ws + WS_EXACT_OFF);
    int*   ws_cnt    = (int*)  (ws + WS_CNT_OFF);
    float* ws_pf     = (float*)(ws + WS_PF_OFF);
    u16*   ws_wh     = (u16*)  (ws + WS_WH_OFF);
    u16*   ws_wl     = (u16*)  (ws + WS_WL_OFF);

    k0_splitW<<<17, 256, 0, stream>>>(w1a, ws_wh, ws_wl, ws_logits);
    k1_pair_mfma<<<dim3(2, NN, RR), 256, 0, stream>>>(obj, geo, ws_wh, ws_wl, b1a, w2a, ws_logits);
    k2_hist<<<1, 1024, 0, stream>>>(ws_logits, mask, b2a, out, ws_cand, ws_cnt);
    k5_exact<<<NCAND, 256, 0, stream>>>(obj, geo, w1a, b1a, w2a, b2a, ws_cand, ws_cnt, ws_exact);
    k_sortgather<<<KTOP, 256, 0, stream>>>(ws_exact, ws_cand, obj, geo, out, ws_pf);
    k4_p2p<<<KTOP, 256, 0, stream>>>(ws_pf, w1b, b1b, w2b, b2b, out);
}